// Round 13
// baseline (255.049 us; speedup 1.0000x reference)
//
#include <hip/hip_runtime.h>

namespace {
constexpr int kB = 2;
constexpr int kH = 12;
constexpr int kD = 64;
constexpr int kC = 768;
constexpr int kF = 8;
constexpr int kP = 196;
constexpr int kS = kF * kP;      // 1568
constexpr int kN = 1 + kS;       // 1569
constexpr int k3C = 3 * kC;      // 2304
constexpr float kScale = 0.125f; // d^-0.5 (exact power of 2)
constexpr int kBH = kB * kH;     // 24
constexpr int kPpad = 224;       // keys padded (max touched key-offset 223)
constexpr int kLpad = 1600;      // cls logits row stride
constexpr int kBS = kB * kS;     // 3136
}

typedef __attribute__((ext_vector_type(8))) short bf16x8;
typedef __attribute__((ext_vector_type(8))) unsigned short u16x8;
typedef __attribute__((ext_vector_type(4))) float f32x4;
typedef __attribute__((ext_vector_type(4))) unsigned int u32x4;

__device__ inline ushort f2bf(float x) {
  union { float f; unsigned u; } v{x};
  unsigned r = v.u + 0x7fff + ((v.u >> 16) & 1);
  return (ushort)(r >> 16);
}
__device__ inline float bf2f(ushort u) {
  union { unsigned u; float f; } v{(unsigned)u << 16};
  return v.f;
}

__device__ __forceinline__ void gload_lds16(const void* g, void* l) {
  __builtin_amdgcn_global_load_lds(
      (const __attribute__((address_space(1))) unsigned int*)g,
      (__attribute__((address_space(3))) unsigned int*)l, 16, 0, 0);
}

__device__ inline void storeC(float v, float* p) { *p = v; }
__device__ inline void storeC(float v, ushort* p) { *p = f2bf(v); }

// ---------- bf16 MFMA GEMM: C[M,N] = A[M,K]bf16 @ Bt[N,K]bf16^T (+bias) ----
template <typename OutT>
__global__ __launch_bounds__(256) void gemm_bf16(
    const ushort* __restrict__ A, const ushort* __restrict__ Bt,
    const float* __restrict__ bias, OutT* __restrict__ C,
    int M, int N, int K, int nbx) {
  const int nwg = gridDim.x;
  const int q = nwg >> 3, rr = nwg & 7;
  const int xcd = blockIdx.x & 7, loc = blockIdx.x >> 3;
  const int vid = ((xcd < rr) ? xcd * (q + 1) : rr * (q + 1) + (xcd - rr) * q) + loc;
  const int m0 = (vid / nbx) * 128, n0 = (vid % nbx) * 128;

  __shared__ __align__(16) ushort As[128 * 32];
  __shared__ __align__(16) ushort Bs[128 * 32];
  const int tid = threadIdx.x;
  const int r0 = tid >> 2, c0 = tid & 3;
  const int r1 = r0 + 64;
  const int sc0 = (c0 ^ ((r0 >> 1) & 3)) * 8;
  const int sc1 = (c0 ^ ((r1 >> 1) & 3)) * 8;
  const int ar0 = min(m0 + r0, M - 1), ar1 = min(m0 + r1, M - 1);
  const ushort* ga0 = A + (size_t)ar0 * K + sc0;
  const ushort* ga1 = A + (size_t)ar1 * K + sc1;
  const ushort* gb0 = Bt + (size_t)(n0 + r0) * K + sc0;
  const ushort* gb1 = Bt + (size_t)(n0 + r1) * K + sc1;
  const int w = tid >> 6;
  char* lA0 = (char*)As + w * 1024;
  char* lA1 = (char*)As + 4096 + w * 1024;
  char* lB0 = (char*)Bs + w * 1024;
  char* lB1 = (char*)Bs + 4096 + w * 1024;
  const int lane = tid & 63;
  const int lr = lane & 15, lg = lane >> 4;
  const int wr = w >> 1, wc = w & 1;
  f32x4 acc[4][4] = {};
  for (int kt = 0; kt < K; kt += 32) {
    gload_lds16(ga0 + kt, lA0);
    gload_lds16(ga1 + kt, lA1);
    gload_lds16(gb0 + kt, lB0);
    gload_lds16(gb1 + kt, lB1);
    __syncthreads();
    bf16x8 af[4], bfr[4];
#pragma unroll
    for (int m = 0; m < 4; ++m) {
      int row = wr * 64 + m * 16 + lr;
      int ch = lg ^ ((row >> 1) & 3);
      af[m] = *(const bf16x8*)(As + row * 32 + ch * 8);
    }
#pragma unroll
    for (int n = 0; n < 4; ++n) {
      int row = wc * 64 + n * 16 + lr;
      int ch = lg ^ ((row >> 1) & 3);
      bfr[n] = *(const bf16x8*)(Bs + row * 32 + ch * 8);
    }
#pragma unroll
    for (int m = 0; m < 4; ++m)
#pragma unroll
      for (int n = 0; n < 4; ++n)
        acc[m][n] =
            __builtin_amdgcn_mfma_f32_16x16x32_bf16(af[m], bfr[n], acc[m][n], 0, 0, 0);
    __syncthreads();
  }
#pragma unroll
  for (int m = 0; m < 4; ++m) {
#pragma unroll
    for (int r = 0; r < 4; ++r) {
      const int mg = m0 + wr * 64 + m * 16 + lg * 4 + r;
      if (mg < M) {
        OutT* crow = C + (size_t)mg * N + n0 + wc * 64 + lr;
#pragma unroll
        for (int n = 0; n < 4; ++n) {
          float v = acc[m][n][r];
          if (bias) v += bias[n0 + wc * 64 + n * 16 + lr];
          storeC(v, crow + n * 16);
        }
      }
    }
  }
}

// ---------- qkv GEMM with fused Qb/Kb pack epilogue (coalesced only) ----------
__global__ __launch_bounds__(256) void gemm_qkv(
    const ushort* __restrict__ A, const ushort* __restrict__ Bt,
    ushort* __restrict__ qkvb, ushort* __restrict__ Qb,
    ushort* __restrict__ Kb) {
  constexpr int M = 3138, N = k3C, K = kC, nbx = 18;
  const int nwg = gridDim.x;
  const int q = nwg >> 3, rr = nwg & 7;
  const int xcd = blockIdx.x & 7, loc = blockIdx.x >> 3;
  const int vid = ((xcd < rr) ? xcd * (q + 1) : rr * (q + 1) + (xcd - rr) * q) + loc;
  const int m0 = (vid / nbx) * 128, n0 = (vid % nbx) * 128;

  __shared__ __align__(16) ushort As[128 * 32];
  __shared__ __align__(16) ushort Bs[128 * 32];
  const int tid = threadIdx.x;
  const int r0 = tid >> 2, c0 = tid & 3;
  const int r1 = r0 + 64;
  const int sc0 = (c0 ^ ((r0 >> 1) & 3)) * 8;
  const int sc1 = (c0 ^ ((r1 >> 1) & 3)) * 8;
  const int ar0 = min(m0 + r0, M - 1), ar1 = min(m0 + r1, M - 1);
  const ushort* ga0 = A + (size_t)ar0 * K + sc0;
  const ushort* ga1 = A + (size_t)ar1 * K + sc1;
  const ushort* gb0 = Bt + (size_t)(n0 + r0) * K + sc0;
  const ushort* gb1 = Bt + (size_t)(n0 + r1) * K + sc1;
  const int w = tid >> 6;
  char* lA0 = (char*)As + w * 1024;
  char* lA1 = (char*)As + 4096 + w * 1024;
  char* lB0 = (char*)Bs + w * 1024;
  char* lB1 = (char*)Bs + 4096 + w * 1024;
  const int lane = tid & 63;
  const int lr = lane & 15, lg = lane >> 4;
  const int wr = w >> 1, wc = w & 1;
  f32x4 acc[4][4] = {};
  for (int kt = 0; kt < K; kt += 32) {
    gload_lds16(ga0 + kt, lA0);
    gload_lds16(ga1 + kt, lA1);
    gload_lds16(gb0 + kt, lB0);
    gload_lds16(gb1 + kt, lB1);
    __syncthreads();
    bf16x8 af[4], bfr[4];
#pragma unroll
    for (int m = 0; m < 4; ++m) {
      int row = wr * 64 + m * 16 + lr;
      int ch = lg ^ ((row >> 1) & 3);
      af[m] = *(const bf16x8*)(As + row * 32 + ch * 8);
    }
#pragma unroll
    for (int n = 0; n < 4; ++n) {
      int row = wc * 64 + n * 16 + lr;
      int ch = lg ^ ((row >> 1) & 3);
      bfr[n] = *(const bf16x8*)(Bs + row * 32 + ch * 8);
    }
#pragma unroll
    for (int m = 0; m < 4; ++m)
#pragma unroll
      for (int n = 0; n < 4; ++n)
        acc[m][n] =
            __builtin_amdgcn_mfma_f32_16x16x32_bf16(af[m], bfr[n], acc[m][n], 0, 0, 0);
    __syncthreads();
  }
#pragma unroll
  for (int m = 0; m < 4; ++m) {
#pragma unroll
    for (int r = 0; r < 4; ++r) {
      const int mg = m0 + wr * 64 + m * 16 + lg * 4 + r;
      if (mg >= M) continue;
      const int b = (mg >= kN) ? 1 : 0;
      const int tok = mg - b * kN;
      ushort* qrow = qkvb + (size_t)mg * k3C + n0 + wc * 64 + lr;
#pragma unroll
      for (int n = 0; n < 4; ++n) {
        const int col = n0 + wc * 64 + n * 16 + lr;
        const float v = acc[m][n][r];
        const ushort bv = f2bf(v);
        qrow[n * 16] = bv;
        if (tok >= 1) {
          const int s = tok - 1;
          const int sec = col / kC;
          const int cj = col - sec * kC;
          const int h = cj >> 6, j = cj & 63;
          const int bh = b * kH + h;
          if (sec == 0) {
            Qb[((size_t)bh * kS + s) * kD + j] = f2bf(v * kScale);
          } else if (sec == 1) {
            Kb[((size_t)bh * kS + s) * kD + j] = bv;
          }
          // sec==2 (V): written by pack_vt_k (coalesced) — fused scatter was
          // a measured regression (r11: 448B-stride 2B writes).
        }
      }
    }
  }
}

// ---------- q2 GEMM with fused xd gather: A-row = x4b diagonal ----------
__global__ __launch_bounds__(256) void gemm_q2(
    const ushort* __restrict__ x4b, const ushort* __restrict__ Bt,
    ushort* __restrict__ C) {
  constexpr int M = kBS, N = kC, K = kC, nbx = 6;
  const int nwg = gridDim.x;
  const int q = nwg >> 3, rr = nwg & 7;
  const int xcd = blockIdx.x & 7, loc = blockIdx.x >> 3;
  const int vid = ((xcd < rr) ? xcd * (q + 1) : rr * (q + 1) + (xcd - rr) * q) + loc;
  const int m0 = (vid / nbx) * 128, n0 = (vid % nbx) * 128;

  __shared__ __align__(16) ushort As[128 * 32];
  __shared__ __align__(16) ushort Bs[128 * 32];
  const int tid = threadIdx.x;
  const int r0 = tid >> 2, c0 = tid & 3;
  const int r1 = r0 + 64;
  const int sc0 = (c0 ^ ((r0 >> 1) & 3)) * 8;
  const int sc1 = (c0 ^ ((r1 >> 1) & 3)) * 8;
  const int ar0 = min(m0 + r0, M - 1), ar1 = min(m0 + r1, M - 1);
  const int fq0 = (ar0 % kS) / kP, fq1 = (ar1 % kS) / kP;
  const ushort* ga0 = x4b + ((size_t)ar0 * kF + fq0) * kC + sc0;
  const ushort* ga1 = x4b + ((size_t)ar1 * kF + fq1) * kC + sc1;
  const ushort* gb0 = Bt + (size_t)(n0 + r0) * K + sc0;
  const ushort* gb1 = Bt + (size_t)(n0 + r1) * K + sc1;
  const int w = tid >> 6;
  char* lA0 = (char*)As + w * 1024;
  char* lA1 = (char*)As + 4096 + w * 1024;
  char* lB0 = (char*)Bs + w * 1024;
  char* lB1 = (char*)Bs + 4096 + w * 1024;
  const int lane = tid & 63;
  const int lr = lane & 15, lg = lane >> 4;
  const int wr = w >> 1, wc = w & 1;
  f32x4 acc[4][4] = {};
  for (int kt = 0; kt < K; kt += 32) {
    gload_lds16(ga0 + kt, lA0);
    gload_lds16(ga1 + kt, lA1);
    gload_lds16(gb0 + kt, lB0);
    gload_lds16(gb1 + kt, lB1);
    __syncthreads();
    bf16x8 af[4], bfr[4];
#pragma unroll
    for (int m = 0; m < 4; ++m) {
      int row = wr * 64 + m * 16 + lr;
      int ch = lg ^ ((row >> 1) & 3);
      af[m] = *(const bf16x8*)(As + row * 32 + ch * 8);
    }
#pragma unroll
    for (int n = 0; n < 4; ++n) {
      int row = wc * 64 + n * 16 + lr;
      int ch = lg ^ ((row >> 1) & 3);
      bfr[n] = *(const bf16x8*)(Bs + row * 32 + ch * 8);
    }
#pragma unroll
    for (int m = 0; m < 4; ++m)
#pragma unroll
      for (int n = 0; n < 4; ++n)
        acc[m][n] =
            __builtin_amdgcn_mfma_f32_16x16x32_bf16(af[m], bfr[n], acc[m][n], 0, 0, 0);
    __syncthreads();
  }
#pragma unroll
  for (int m = 0; m < 4; ++m) {
#pragma unroll
    for (int r = 0; r < 4; ++r) {
      const int mg = m0 + wr * 64 + m * 16 + lg * 4 + r;
      if (mg < M) {
        ushort* crow = C + (size_t)mg * N + n0 + wc * 64 + lr;
#pragma unroll
        for (int n = 0; n < 4; ++n) crow[n * 16] = f2bf(acc[m][n][r]);
      }
    }
  }
}

// ---------- w2[bs][h][c] = sum_d q2b[bs][h*64+d] * Wkvb[c][h*64+d] ----------
__global__ __launch_bounds__(256) void w2_gemm(
    const ushort* __restrict__ q2b, const ushort* __restrict__ Wkvb,
    ushort* __restrict__ w2b) {
  const int nwg = gridDim.x;
  const int q = nwg >> 3, rr = nwg & 7;
  const int xcd = blockIdx.x & 7, loc = blockIdx.x >> 3;
  const int vid = ((xcd < rr) ? xcd * (q + 1) : rr * (q + 1) + (xcd - rr) * q) + loc;
  const int h = vid / 150;
  const int rem = vid - h * 150;
  const int m0 = (rem / 6) * 128, n0 = (rem % 6) * 128;

  __shared__ __align__(16) ushort As[128 * 32];
  __shared__ __align__(16) ushort Bs[128 * 32];
  const int tid = threadIdx.x;
  const int r0 = tid >> 2, c0 = tid & 3;
  const int r1 = r0 + 64;
  const int sc0 = (c0 ^ ((r0 >> 1) & 3)) * 8;
  const int sc1 = (c0 ^ ((r1 >> 1) & 3)) * 8;
  const int ar0 = min(m0 + r0, kBS - 1), ar1 = min(m0 + r1, kBS - 1);
  const ushort* ga0 = q2b + (size_t)ar0 * kC + h * 64 + sc0;
  const ushort* ga1 = q2b + (size_t)ar1 * kC + h * 64 + sc1;
  const ushort* gb0 = Wkvb + (size_t)(n0 + r0) * kC + h * 64 + sc0;
  const ushort* gb1 = Wkvb + (size_t)(n0 + r1) * kC + h * 64 + sc1;
  const int w = tid >> 6;
  char* lA0 = (char*)As + w * 1024;
  char* lA1 = (char*)As + 4096 + w * 1024;
  char* lB0 = (char*)Bs + w * 1024;
  char* lB1 = (char*)Bs + 4096 + w * 1024;
  const int lane = tid & 63;
  const int lr = lane & 15, lg = lane >> 4;
  const int wr = w >> 1, wc = w & 1;
  f32x4 acc[4][4] = {};
#pragma unroll
  for (int kt = 0; kt < 64; kt += 32) {
    gload_lds16(ga0 + kt, lA0);
    gload_lds16(ga1 + kt, lA1);
    gload_lds16(gb0 + kt, lB0);
    gload_lds16(gb1 + kt, lB1);
    __syncthreads();
    bf16x8 af[4], bfr[4];
#pragma unroll
    for (int m = 0; m < 4; ++m) {
      int row = wr * 64 + m * 16 + lr;
      int ch = lg ^ ((row >> 1) & 3);
      af[m] = *(const bf16x8*)(As + row * 32 + ch * 8);
    }
#pragma unroll
    for (int n = 0; n < 4; ++n) {
      int row = wc * 64 + n * 16 + lr;
      int ch = lg ^ ((row >> 1) & 3);
      bfr[n] = *(const bf16x8*)(Bs + row * 32 + ch * 8);
    }
#pragma unroll
    for (int m = 0; m < 4; ++m)
#pragma unroll
      for (int n = 0; n < 4; ++n)
        acc[m][n] =
            __builtin_amdgcn_mfma_f32_16x16x32_bf16(af[m], bfr[n], acc[m][n], 0, 0, 0);
    __syncthreads();
  }
#pragma unroll
  for (int m = 0; m < 4; ++m) {
#pragma unroll
    for (int r = 0; r < 4; ++r) {
      const int mg = m0 + wr * 64 + m * 16 + lg * 4 + r;
      if (mg < kBS) {
        ushort* crow = w2b + (size_t)mg * (kH * kC) + h * kC + n0 + wc * 64 + lr;
#pragma unroll
        for (int n = 0; n < 4; ++n) crow[n * 16] = f2bf(acc[m][n][r]);
      }
    }
  }
}

// ---------- merged packs: x->bf16, 3 weight transposes, Wkv copy ----------
// flat grid (5810): [0,2354) pack_x | [2354,4082) Wqkv_t | [4082,4658) Wq_t |
// [4658,5234) Wproj_t | [5234,5810) Wkvb
__global__ __launch_bounds__(256) void pack_all_k(
    const float* __restrict__ x, const float* __restrict__ Wqkv,
    const float* __restrict__ Wq, const float* __restrict__ Wproj,
    const float* __restrict__ Wkv, ushort* __restrict__ xb,
    ushort* __restrict__ Wqkv_t, ushort* __restrict__ Wq_t,
    ushort* __restrict__ Wproj_t, ushort* __restrict__ Wkvb) {
  __shared__ float t[32][33];
  int bid = blockIdx.x;
  if (bid < 2354) {
    const int i = bid * 256 + threadIdx.x;
    if (i < 3138 * 768 / 4) {  // 602,496 float4s
      float4 v = ((const float4*)x)[i];
      ushort4 o = {f2bf(v.x), f2bf(v.y), f2bf(v.z), f2bf(v.w)};
      ((ushort4*)xb)[i] = o;
    }
    return;
  }
  bid -= 2354;
  if (bid < 2880) {
    const float* W;
    ushort* Wt;
    int ldw, nbw;
    float scale;
    if (bid < 1728) {
      W = Wqkv; Wt = Wqkv_t; ldw = 2304; nbw = 72; scale = 1.f;
    } else if (bid < 2304) {
      bid -= 1728;
      W = Wq; Wt = Wq_t; ldw = 768; nbw = 24; scale = kScale;
    } else {
      bid -= 2304;
      W = Wproj; Wt = Wproj_t; ldw = 768; nbw = 24; scale = 1.f;
    }
    const int nb = (bid % nbw) * 32, kb = (bid / nbw) * 32;
    const int tx = threadIdx.x & 31, ty = threadIdx.x >> 5;
#pragma unroll
    for (int i = 0; i < 32; i += 8)
      t[ty + i][tx] = W[(size_t)(kb + ty + i) * ldw + nb + tx];
    __syncthreads();
#pragma unroll
    for (int i = 0; i < 32; i += 8)
      Wt[(size_t)(nb + ty + i) * 768 + kb + tx] = f2bf(t[tx][ty + i] * scale);
    return;
  }
  bid -= 2880;
  const int i = bid * 256 + threadIdx.x;  // < 576*256 == 768*192 exactly
  const int c = i / 192, j4 = i - c * 192;
  float4 v = *(const float4*)(Wkv + (size_t)c * 1536 + j4 * 4);
  ushort4 o = {f2bf(v.x), f2bf(v.y), f2bf(v.z), f2bf(v.w)};
  *(ushort4*)(Wkvb + (size_t)c * 768 + j4 * 4) = o;
}

// ---------- pack V transposed: Vt[bh*8+f][64][224] bf16 (coalesced) ----------
__global__ void pack_vt_k(const ushort* __restrict__ qkvb,
                          ushort* __restrict__ Vt) {
  const int idx = blockIdx.x * 256 + threadIdx.x;
  if (idx >= kBH * kF * kD * kPpad) return;
  const int n = idx % kPpad;
  const int j = (idx / kPpad) & 63;
  const int f = (idx / (kPpad * kD)) & 7;
  const int bh = idx / (kPpad * kD * kF);
  const int b = bh / kH, h = bh % kH;
  ushort v = 0;
  if (n < kP)
    v = qkvb[(size_t)(b * kN + 1 + f * kP + n) * k3C + 2 * kC + h * kD + j];
  Vt[idx] = v;
}

// ---------- spatial attention, swapped-QK^T, LDS-free (r9 shape + setprio) ----
__global__ __launch_bounds__(256) void sp_attn_mfma(
    const ushort* __restrict__ Qb, const ushort* __restrict__ Kb,
    const ushort* __restrict__ Vt, ushort* __restrict__ x4b) {
  const int w = threadIdx.x >> 6;
  const int lane = threadIdx.x & 63;
  const int fbh = blockIdx.x;
  const int f = fbh / 24, bh = fbh % 24;
  const int tile = blockIdx.y * 4 + w;  // 0..48 valid
  if (tile >= 49) return;
  const int q0 = tile * 32;
  const int lr = lane & 15;
  const int lg = lane >> 4;

  const ushort* qrow = Qb + ((size_t)bh * kS + q0 + lr) * kD + lg * 8;
  const bf16x8 a00 = *(const bf16x8*)qrow;
  const bf16x8 a01 = *(const bf16x8*)(qrow + 32);
  const bf16x8 a10 = *(const bf16x8*)(qrow + 16 * kD);
  const bf16x8 a11 = *(const bf16x8*)(qrow + 16 * kD + 32);

  f32x4 s0[13], s1[13];
  const ushort* kbase = Kb + ((size_t)bh * kS + f * kP + lr) * kD + lg * 8;
  __builtin_amdgcn_s_setprio(1);
#pragma unroll
  for (int nt = 0; nt < 13; ++nt) {
    const ushort* kr = kbase + (size_t)nt * 16 * kD;
    bf16x8 b0 = *(const bf16x8*)kr;
    bf16x8 b1 = *(const bf16x8*)(kr + 32);
    f32x4 acc0 = {0.f, 0.f, 0.f, 0.f}, acc1 = {0.f, 0.f, 0.f, 0.f};
    acc0 = __builtin_amdgcn_mfma_f32_16x16x32_bf16(b0, a00, acc0, 0, 0, 0);
    acc0 = __builtin_amdgcn_mfma_f32_16x16x32_bf16(b1, a01, acc0, 0, 0, 0);
    acc1 = __builtin_amdgcn_mfma_f32_16x16x32_bf16(b0, a10, acc1, 0, 0, 0);
    acc1 = __builtin_amdgcn_mfma_f32_16x16x32_bf16(b1, a11, acc1, 0, 0, 0);
    s0[nt] = acc0;
    s1[nt] = acc1;
  }
  __builtin_amdgcn_s_setprio(0);
  if (lg >= 1) {
#pragma unroll
    for (int r = 0; r < 4; ++r) { s0[12][r] = -1e30f; s1[12][r] = -1e30f; }
  }

  float m0 = -1e30f, m1 = -1e30f;
#pragma unroll
  for (int nt = 0; nt < 13; ++nt)
#pragma unroll
    for (int r = 0; r < 4; ++r) {
      m0 = fmaxf(m0, s0[nt][r]);
      m1 = fmaxf(m1, s1[nt][r]);
    }
  m0 = fmaxf(m0, __shfl_xor(m0, 16));
  m0 = fmaxf(m0, __shfl_xor(m0, 32));
  m1 = fmaxf(m1, __shfl_xor(m1, 16));
  m1 = fmaxf(m1, __shfl_xor(m1, 32));

  float sum0 = 0.f, sum1 = 0.f;
  u32x4 breg0[7], breg1[7];
#pragma unroll
  for (int blk = 0; blk < 7; ++blk) {
    unsigned pk0[2][2], pk1[2][2];
#pragma unroll
    for (int t = 0; t < 2; ++t) {
      const int nt = blk * 2 + t;
      if (nt < 13) {
        float e0 = __expf(s0[nt][0] - m0), e1 = __expf(s0[nt][1] - m0);
        float e2 = __expf(s0[nt][2] - m0), e3 = __expf(s0[nt][3] - m0);
        sum0 += (e0 + e1) + (e2 + e3);
        pk0[t][0] = ((unsigned)f2bf(e1) << 16) | f2bf(e0);
        pk0[t][1] = ((unsigned)f2bf(e3) << 16) | f2bf(e2);
        float g0 = __expf(s1[nt][0] - m1), g1 = __expf(s1[nt][1] - m1);
        float g2 = __expf(s1[nt][2] - m1), g3 = __expf(s1[nt][3] - m1);
        sum1 += (g0 + g1) + (g2 + g3);
        pk1[t][0] = ((unsigned)f2bf(g1) << 16) | f2bf(g0);
        pk1[t][1] = ((unsigned)f2bf(g3) << 16) | f2bf(g2);
      } else {
        pk0[t][0] = 0; pk0[t][1] = 0;
        pk1[t][0] = 0; pk1[t][1] = 0;
      }
    }
#pragma unroll
    for (int j2 = 0; j2 < 4; ++j2) {
      const int srcLane = ((lg & 1) * 2 + (j2 >> 1)) * 16 + lr;
      unsigned t0 = (unsigned)__shfl((int)pk0[0][j2 & 1], srcLane);
      unsigned t1 = (unsigned)__shfl((int)pk0[1][j2 & 1], srcLane);
      breg0[blk][j2] = (lg < 2) ? t0 : t1;
      unsigned u0 = (unsigned)__shfl((int)pk1[0][j2 & 1], srcLane);
      unsigned u1 = (unsigned)__shfl((int)pk1[1][j2 & 1], srcLane);
      breg1[blk][j2] = (lg < 2) ? u0 : u1;
    }
  }
  sum0 += __shfl_xor(sum0, 16);
  sum0 += __shfl_xor(sum0, 32);
  sum1 += __shfl_xor(sum1, 16);
  sum1 += __shfl_xor(sum1, 32);
  const float inv0 = 1.f / sum0, inv1 = 1.f / sum1;

  const ushort* vbase = Vt + ((size_t)(bh * kF + f) * kD + lr) * kPpad + lg * 8;
  f32x4 o0[4] = {}, o1[4] = {};
  __builtin_amdgcn_s_setprio(1);
#pragma unroll
  for (int nt2 = 0; nt2 < 4; ++nt2) {
    const ushort* vb = vbase + (size_t)nt2 * 16 * kPpad;
#pragma unroll
    for (int blk = 0; blk < 7; ++blk) {
      bf16x8 av = *(const bf16x8*)(vb + blk * 32);
      bf16x8 pb0 = __builtin_bit_cast(bf16x8, breg0[blk]);
      bf16x8 pb1 = __builtin_bit_cast(bf16x8, breg1[blk]);
      o0[nt2] = __builtin_amdgcn_mfma_f32_16x16x32_bf16(av, pb0, o0[nt2], 0, 0, 0);
      o1[nt2] = __builtin_amdgcn_mfma_f32_16x16x32_bf16(av, pb1, o1[nt2], 0, 0, 0);
    }
  }
  __builtin_amdgcn_s_setprio(0);

  const int b = bh / kH, h = bh % kH;
  const size_t base0 =
      ((size_t)(b * kS + q0 + lr) * kF + f) * kC + h * kD + lg * 4;
#pragma unroll
  for (int nt2 = 0; nt2 < 4; ++nt2) {
    ushort4 v0, v1;
    v0.x = f2bf(o0[nt2][0] * inv0);
    v0.y = f2bf(o0[nt2][1] * inv0);
    v0.z = f2bf(o0[nt2][2] * inv0);
    v0.w = f2bf(o0[nt2][3] * inv0);
    *(ushort4*)(x4b + base0 + nt2 * 16) = v0;
    v1.x = f2bf(o1[nt2][0] * inv1);
    v1.y = f2bf(o1[nt2][1] * inv1);
    v1.z = f2bf(o1[nt2][2] * inv1);
    v1.w = f2bf(o1[nt2][3] * inv1);
    *(ushort4*)(x4b + base0 + (size_t)16 * kF * kC + nt2 * 16) = v1;
  }
}

// ---------- cls attention, 4-phase parallel (bf16 qkv) ----------
__global__ __launch_bounds__(256) void cls_logits_k(const ushort* __restrict__ qkvb,
                                                    float* __restrict__ logits) {
  const int chunk = blockIdx.x, bh = blockIdx.y;
  const int b = bh / kH, h = bh % kH;
  const int g = threadIdx.x & 15, row = threadIdx.x >> 4;
  const size_t base = (size_t)b * kN * k3C;
  const ushort* qp = qkvb + base + h * kD + g * 4;
  const float q0 = bf2f(qp[0]) * kScale, q1 = bf2f(qp[1]) * kScale;
  const float q2 = bf2f(qp[2]) * kScale, q3 = bf2f(qp[3]) * kScale;
#pragma unroll
  for (int i = 0; i < 16; ++i) {
    const int n = chunk * 256 + i * 16 + row;
    if (n < kN) {
      ushort4 kv =
          *(const ushort4*)(qkvb + base + (size_t)n * k3C + kC + h * kD + g * 4);
      float p = q0 * bf2f(kv.x) + q1 * bf2f(kv.y) + q2 * bf2f(kv.z) +
                q3 * bf2f(kv.w);
#pragma unroll
      for (int o = 8; o; o >>= 1) p += __shfl_xor(p, o, 16);
      if (g == 0) logits[bh * kLpad + n] = p;
    }
  }
}

__global__ __launch_bounds__(256) void cls_softmax_k(const float* __restrict__ logits,
                                                     float* __restrict__ pbuf) {
  __shared__ float red[8];
  const int bh = blockIdx.x, tid = threadIdx.x;
  float m = -1e30f;
  for (int n = tid; n < kN; n += 256) m = fmaxf(m, logits[bh * kLpad + n]);
#pragma unroll
  for (int o = 32; o; o >>= 1) m = fmaxf(m, __shfl_xor(m, o));
  if ((tid & 63) == 0) red[tid >> 6] = m;
  __syncthreads();
  m = fmaxf(fmaxf(red[0], red[1]), fmaxf(red[2], red[3]));
  float sum = 0.f;
  for (int n = tid; n < kN; n += 256) sum += __expf(logits[bh * kLpad + n] - m);
#pragma unroll
  for (int o = 32; o; o >>= 1) sum += __shfl_xor(sum, o);
  if ((tid & 63) == 0) red[4 + (tid >> 6)] = sum;
  __syncthreads();
  const float inv = 1.f / (red[4] + red[5] + red[6] + red[7]);
  for (int n = tid; n < kN; n += 256)
    pbuf[bh * kLpad + n] = __expf(logits[bh * kLpad + n] - m) * inv;
}

__global__ __launch_bounds__(256) void cls_pv_k(const ushort* __restrict__ qkvb,
                                                const float* __restrict__ pbuf,
                                                float* __restrict__ partial) {
  __shared__ float pb[256];
  const int chunk = blockIdx.x, bh = blockIdx.y;
  const int b = bh / kH, h = bh % kH;
  const int j = threadIdx.x & 63, part = threadIdx.x >> 6;
  const size_t base = (size_t)b * kN * k3C + 2 * kC + h * kD + j;
  float acc = 0.f;
#pragma unroll 4
  for (int i = 0; i < 64; ++i) {
    const int n = chunk * 256 + i * 4 + part;
    if (n < kN)
      acc = fmaf(pbuf[bh * kLpad + n], bf2f(qkvb[base + (size_t)n * k3C]), acc);
  }
  pb[threadIdx.x] = acc;
  __syncthreads();
  if (part == 0)
    partial[((size_t)bh * 7 + chunk) * kD + j] =
        pb[j] + pb[64 + j] + pb[128 + j] + pb[192 + j];
}

__global__ void cls_red_k(const float* __restrict__ partial,
                          ushort* __restrict__ xin_b) {
  const int bh = blockIdx.x, j = threadIdx.x;
  const int b = bh / kH, h = bh % kH;
  float s = 0.f;
#pragma unroll
  for (int c = 0; c < 7; ++c) s += partial[((size_t)bh * 7 + c) * kD + j];
  xin_b[(size_t)(b * kN) * kC + h * kD + j] = f2bf(s);
}

// ---------- fused temporal attention: one block per (b,s) ----------
__global__ __launch_bounds__(256) void attn2_fused(
    const ushort* __restrict__ x4b, const ushort* __restrict__ w2b,
    ushort* __restrict__ xin_b, float* __restrict__ attn2out) {
  __shared__ __align__(16) ushort x4s[kF * kC];
  __shared__ __align__(16) ushort w2s[kH * kC];
  const int bs = blockIdx.x;
  const int b = bs / kS, s = bs - b * kS;
  const int tid = threadIdx.x;
  {
    const ulonglong2* src = (const ulonglong2*)(x4b + (size_t)bs * kF * kC);
    ulonglong2* dst = (ulonglong2*)x4s;
    for (int i = tid; i < kF * kC / 8; i += 256) dst[i] = src[i];
    const ulonglong2* srcw = (const ulonglong2*)(w2b + (size_t)bs * kH * kC);
    ulonglong2* dstw = (ulonglong2*)w2s;
    for (int i = tid; i < kH * kC / 8; i += 256) dstw[i] = srcw[i];
  }
  __syncthreads();
  const int w = tid >> 6, lane = tid & 63;
#pragma unroll
  for (int hh = 0; hh < 3; ++hh) {
    const int h = w * 3 + hh;
    float part[kF] = {};
#pragma unroll
    for (int i = 0; i < 3; ++i) {
      const int c = lane * 4 + i * 256;
      ushort4 wv = *(const ushort4*)&w2s[h * kC + c];
      const float w0 = bf2f(wv.x), w1 = bf2f(wv.y);
      const float w2v = bf2f(wv.z), w3 = bf2f(wv.w);
#pragma unroll
      for (int f = 0; f < kF; ++f) {
        ushort4 xv = *(const ushort4*)&x4s[f * kC + c];
        part[f] += bf2f(xv.x) * w0 + bf2f(xv.y) * w1 + bf2f(xv.z) * w2v +
                   bf2f(xv.w) * w3;
      }
    }
    float l[kF];
#pragma unroll
    for (int f = 0; f < kF; ++f) {
      float p = part[f];
#pragma unroll
      for (int o = 32; o; o >>= 1) p += __shfl_xor(p, o);
      l[f] = p;
    }
    float m = l[0];
#pragma unroll
    for (int f = 1; f < kF; ++f) m = fmaxf(m, l[f]);
    float sum = 0.f;
#pragma unroll
    for (int f = 0; f < kF; ++f) {
      l[f] = __expf(l[f] - m);
      sum += l[f];
    }
    const float inv = 1.f / sum;
    float pv = 0.f;
#pragma unroll
    for (int f = 0; f < kF; ++f) pv = (lane == f) ? l[f] : pv;
    if (lane < kF)
      attn2out[((size_t)(b * kH + h) * kS + s) * kF + lane] = pv * inv;
    float o = 0.f;
#pragma unroll
    for (int f = 0; f < kF; ++f)
      o = fmaf(l[f] * inv, bf2f(x4s[f * kC + h * kD + lane]), o);
    xin_b[(size_t)(b * kN + 1 + s) * kC + h * kD + lane] = f2bf(o);
  }
}

extern "C" void kernel_launch(void* const* d_in, const int* in_sizes, int n_in,
                              void* d_out, int out_size, void* d_ws,
                              size_t ws_size, hipStream_t stream) {
  const float* x = (const float*)d_in[0];
  const float* Wqkv = (const float*)d_in[1];
  const float* Wq = (const float*)d_in[2];
  const float* Wkv = (const float*)d_in[3];
  const float* Wproj = (const float*)d_in[4];
  const float* bproj = (const float*)d_in[5];

  char* p = (char*)d_ws;
  ushort* qkvb = (ushort*)p;         p += (size_t)3138 * 2304 * 2;
  ushort* w2b = (ushort*)p;          p += (size_t)kBS * kH * kC * 2;
  ushort* q2b = (ushort*)p;          p += (size_t)kBS * kC * 2;
  ushort* x4b = (ushort*)p;          p += (size_t)25088 * 768 * 2;
  ushort* xin_b = (ushort*)p;        p += (size_t)3138 * 768 * 2;
  ushort* xb = (ushort*)p;           p += (size_t)3138 * 768 * 2;
  ushort* Wqkv_t = (ushort*)p;       p += (size_t)2304 * 768 * 2;
  ushort* Wq_t = (ushort*)p;         p += (size_t)768 * 768 * 2;
  ushort* Wkvb = (ushort*)p;         p += (size_t)768 * 768 * 2;
  ushort* Wproj_t = (ushort*)p;      p += (size_t)768 * 768 * 2;
  ushort* Qb = (ushort*)p;           p += (size_t)kBH * kS * kD * 2;
  ushort* Kb = (ushort*)p;           p += ((size_t)kBH * kS + 16) * kD * 2;
  ushort* Vt = (ushort*)p;           p += (size_t)kBH * kF * kD * kPpad * 2;
  float* clsL = (float*)p;           p += (size_t)kBH * kLpad * 4;
  float* clsP = (float*)p;           p += (size_t)kBH * kLpad * 4;
  float* clsPart = (float*)p;

  float* out = (float*)d_out;
  float* attn2 = out + (size_t)kB * kN * kC;

  // 0. merged packs (x + 4 weights); grid 5810 = 2354 + 2880 + 576
  pack_all_k<<<5810, 256, 0, stream>>>(x, Wqkv, Wq, Wproj, Wkv, xb, Wqkv_t,
                                       Wq_t, Wproj_t, Wkvb);
  // 1. qkv GEMM with fused Qb/Kb pack -> qkvb, Qb, Kb
  gemm_qkv<<<18 * 25, 256, 0, stream>>>(xb, Wqkv_t, qkvb, Qb, Kb);
  // 2. Vt pack (coalesced)
  pack_vt_k<<<(kBH * kF * kD * kPpad + 255) / 256, 256, 0, stream>>>(qkvb, Vt);
  // 3. cls attention (4-phase)
  cls_logits_k<<<dim3(7, 24), 256, 0, stream>>>(qkvb, clsL);
  cls_softmax_k<<<24, 256, 0, stream>>>(clsL, clsP);
  cls_pv_k<<<dim3(7, 24), 256, 0, stream>>>(qkvb, clsP, clsPart);
  cls_red_k<<<24, 64, 0, stream>>>(clsPart, xin_b);
  // 4. spatial attention -> x4b (r9 4-wave shape + setprio)
  sp_attn_mfma<<<dim3(192, 13), 256, 0, stream>>>(Qb, Kb, Vt, x4b);
  // 5. q2 = diag(x4) @ (Wq*scale)  (fused xd gather)
  gemm_q2<<<6 * 25, 256, 0, stream>>>(x4b, Wq_t, q2b);
  // 6. w2[bs,h,:] = Wkv_h^T @ q2[bs,h,:]
  w2_gemm<<<1800, 256, 0, stream>>>(q2b, Wkvb, w2b);
  // 7. fused temporal attention
  attn2_fused<<<kBS, 256, 0, stream>>>(x4b, w2b, xin_b, attn2);
  // 8. out = xin @ Wproj + bproj
  gemm_bf16<float><<<6 * 25, 256, 0, stream>>>(xin_b, Wproj_t, bproj, out, 3138,
                                               768, 768, 6);
}

// Round 14
// 248.680 us; speedup vs baseline: 1.0256x; 1.0256x over previous
//
#include <hip/hip_runtime.h>

namespace {
constexpr int kB = 2;
constexpr int kH = 12;
constexpr int kD = 64;
constexpr int kC = 768;
constexpr int kF = 8;
constexpr int kP = 196;
constexpr int kS = kF * kP;      // 1568
constexpr int kN = 1 + kS;       // 1569
constexpr int k3C = 3 * kC;      // 2304
constexpr float kScale = 0.125f; // d^-0.5 (exact power of 2)
constexpr int kBH = kB * kH;     // 24
constexpr int kPpad = 224;       // keys padded (max touched key-offset 223)
constexpr int kLpad = 1600;      // cls logits row stride
constexpr int kBS = kB * kS;     // 3136
}

typedef __attribute__((ext_vector_type(8))) short bf16x8;
typedef __attribute__((ext_vector_type(8))) unsigned short u16x8;
typedef __attribute__((ext_vector_type(4))) float f32x4;
typedef __attribute__((ext_vector_type(4))) unsigned int u32x4;

__device__ inline ushort f2bf(float x) {
  union { float f; unsigned u; } v{x};
  unsigned r = v.u + 0x7fff + ((v.u >> 16) & 1);
  return (ushort)(r >> 16);
}
__device__ inline float bf2f(ushort u) {
  union { unsigned u; float f; } v{(unsigned)u << 16};
  return v.f;
}

__device__ __forceinline__ void gload_lds16(const void* g, void* l) {
  __builtin_amdgcn_global_load_lds(
      (const __attribute__((address_space(1))) unsigned int*)g,
      (__attribute__((address_space(3))) unsigned int*)l, 16, 0, 0);
}

__device__ inline void storeC(float v, float* p) { *p = v; }
__device__ inline void storeC(float v, ushort* p) { *p = f2bf(v); }

// ---------- bf16 MFMA GEMM: C[M,N] = A[M,K]bf16 @ Bt[N,K]bf16^T (+bias) ----
template <typename OutT>
__global__ __launch_bounds__(256) void gemm_bf16(
    const ushort* __restrict__ A, const ushort* __restrict__ Bt,
    const float* __restrict__ bias, OutT* __restrict__ C,
    int M, int N, int K, int nbx) {
  const int nwg = gridDim.x;
  const int q = nwg >> 3, rr = nwg & 7;
  const int xcd = blockIdx.x & 7, loc = blockIdx.x >> 3;
  const int vid = ((xcd < rr) ? xcd * (q + 1) : rr * (q + 1) + (xcd - rr) * q) + loc;
  const int m0 = (vid / nbx) * 128, n0 = (vid % nbx) * 128;

  __shared__ __align__(16) ushort As[128 * 32];
  __shared__ __align__(16) ushort Bs[128 * 32];
  const int tid = threadIdx.x;
  const int r0 = tid >> 2, c0 = tid & 3;
  const int r1 = r0 + 64;
  const int sc0 = (c0 ^ ((r0 >> 1) & 3)) * 8;
  const int sc1 = (c0 ^ ((r1 >> 1) & 3)) * 8;
  const int ar0 = min(m0 + r0, M - 1), ar1 = min(m0 + r1, M - 1);
  const ushort* ga0 = A + (size_t)ar0 * K + sc0;
  const ushort* ga1 = A + (size_t)ar1 * K + sc1;
  const ushort* gb0 = Bt + (size_t)(n0 + r0) * K + sc0;
  const ushort* gb1 = Bt + (size_t)(n0 + r1) * K + sc1;
  const int w = tid >> 6;
  char* lA0 = (char*)As + w * 1024;
  char* lA1 = (char*)As + 4096 + w * 1024;
  char* lB0 = (char*)Bs + w * 1024;
  char* lB1 = (char*)Bs + 4096 + w * 1024;
  const int lane = tid & 63;
  const int lr = lane & 15, lg = lane >> 4;
  const int wr = w >> 1, wc = w & 1;
  f32x4 acc[4][4] = {};
  for (int kt = 0; kt < K; kt += 32) {
    gload_lds16(ga0 + kt, lA0);
    gload_lds16(ga1 + kt, lA1);
    gload_lds16(gb0 + kt, lB0);
    gload_lds16(gb1 + kt, lB1);
    __syncthreads();
    bf16x8 af[4], bfr[4];
#pragma unroll
    for (int m = 0; m < 4; ++m) {
      int row = wr * 64 + m * 16 + lr;
      int ch = lg ^ ((row >> 1) & 3);
      af[m] = *(const bf16x8*)(As + row * 32 + ch * 8);
    }
#pragma unroll
    for (int n = 0; n < 4; ++n) {
      int row = wc * 64 + n * 16 + lr;
      int ch = lg ^ ((row >> 1) & 3);
      bfr[n] = *(const bf16x8*)(Bs + row * 32 + ch * 8);
    }
#pragma unroll
    for (int m = 0; m < 4; ++m)
#pragma unroll
      for (int n = 0; n < 4; ++n)
        acc[m][n] =
            __builtin_amdgcn_mfma_f32_16x16x32_bf16(af[m], bfr[n], acc[m][n], 0, 0, 0);
    __syncthreads();
  }
#pragma unroll
  for (int m = 0; m < 4; ++m) {
#pragma unroll
    for (int r = 0; r < 4; ++r) {
      const int mg = m0 + wr * 64 + m * 16 + lg * 4 + r;
      if (mg < M) {
        OutT* crow = C + (size_t)mg * N + n0 + wc * 64 + lr;
#pragma unroll
        for (int n = 0; n < 4; ++n) {
          float v = acc[m][n][r];
          if (bias) v += bias[n0 + wc * 64 + n * 16 + lr];
          storeC(v, crow + n * 16);
        }
      }
    }
  }
}

// ---------- qkv GEMM with fused Qb/Kb pack epilogue (coalesced only) ----------
__global__ __launch_bounds__(256) void gemm_qkv(
    const ushort* __restrict__ A, const ushort* __restrict__ Bt,
    ushort* __restrict__ qkvb, ushort* __restrict__ Qb,
    ushort* __restrict__ Kb) {
  constexpr int M = 3138, N = k3C, K = kC, nbx = 18;
  const int nwg = gridDim.x;
  const int q = nwg >> 3, rr = nwg & 7;
  const int xcd = blockIdx.x & 7, loc = blockIdx.x >> 3;
  const int vid = ((xcd < rr) ? xcd * (q + 1) : rr * (q + 1) + (xcd - rr) * q) + loc;
  const int m0 = (vid / nbx) * 128, n0 = (vid % nbx) * 128;

  __shared__ __align__(16) ushort As[128 * 32];
  __shared__ __align__(16) ushort Bs[128 * 32];
  const int tid = threadIdx.x;
  const int r0 = tid >> 2, c0 = tid & 3;
  const int r1 = r0 + 64;
  const int sc0 = (c0 ^ ((r0 >> 1) & 3)) * 8;
  const int sc1 = (c0 ^ ((r1 >> 1) & 3)) * 8;
  const int ar0 = min(m0 + r0, M - 1), ar1 = min(m0 + r1, M - 1);
  const ushort* ga0 = A + (size_t)ar0 * K + sc0;
  const ushort* ga1 = A + (size_t)ar1 * K + sc1;
  const ushort* gb0 = Bt + (size_t)(n0 + r0) * K + sc0;
  const ushort* gb1 = Bt + (size_t)(n0 + r1) * K + sc1;
  const int w = tid >> 6;
  char* lA0 = (char*)As + w * 1024;
  char* lA1 = (char*)As + 4096 + w * 1024;
  char* lB0 = (char*)Bs + w * 1024;
  char* lB1 = (char*)Bs + 4096 + w * 1024;
  const int lane = tid & 63;
  const int lr = lane & 15, lg = lane >> 4;
  const int wr = w >> 1, wc = w & 1;
  f32x4 acc[4][4] = {};
  for (int kt = 0; kt < K; kt += 32) {
    gload_lds16(ga0 + kt, lA0);
    gload_lds16(ga1 + kt, lA1);
    gload_lds16(gb0 + kt, lB0);
    gload_lds16(gb1 + kt, lB1);
    __syncthreads();
    bf16x8 af[4], bfr[4];
#pragma unroll
    for (int m = 0; m < 4; ++m) {
      int row = wr * 64 + m * 16 + lr;
      int ch = lg ^ ((row >> 1) & 3);
      af[m] = *(const bf16x8*)(As + row * 32 + ch * 8);
    }
#pragma unroll
    for (int n = 0; n < 4; ++n) {
      int row = wc * 64 + n * 16 + lr;
      int ch = lg ^ ((row >> 1) & 3);
      bfr[n] = *(const bf16x8*)(Bs + row * 32 + ch * 8);
    }
#pragma unroll
    for (int m = 0; m < 4; ++m)
#pragma unroll
      for (int n = 0; n < 4; ++n)
        acc[m][n] =
            __builtin_amdgcn_mfma_f32_16x16x32_bf16(af[m], bfr[n], acc[m][n], 0, 0, 0);
    __syncthreads();
  }
#pragma unroll
  for (int m = 0; m < 4; ++m) {
#pragma unroll
    for (int r = 0; r < 4; ++r) {
      const int mg = m0 + wr * 64 + m * 16 + lg * 4 + r;
      if (mg >= M) continue;
      const int b = (mg >= kN) ? 1 : 0;
      const int tok = mg - b * kN;
      ushort* qrow = qkvb + (size_t)mg * k3C + n0 + wc * 64 + lr;
#pragma unroll
      for (int n = 0; n < 4; ++n) {
        const int col = n0 + wc * 64 + n * 16 + lr;
        const float v = acc[m][n][r];
        const ushort bv = f2bf(v);
        qrow[n * 16] = bv;
        if (tok >= 1) {
          const int s = tok - 1;
          const int sec = col / kC;
          const int cj = col - sec * kC;
          const int h = cj >> 6, j = cj & 63;
          const int bh = b * kH + h;
          if (sec == 0) {
            Qb[((size_t)bh * kS + s) * kD + j] = f2bf(v * kScale);
          } else if (sec == 1) {
            Kb[((size_t)bh * kS + s) * kD + j] = bv;
          }
          // sec==2 (V): written by pack_vt_k (coalesced) — fused scatter was
          // a measured regression (r11: 448B-stride 2B writes).
        }
      }
    }
  }
}

// ---------- q2 GEMM with fused xd gather: A-row = x4b diagonal ----------
__global__ __launch_bounds__(256) void gemm_q2(
    const ushort* __restrict__ x4b, const ushort* __restrict__ Bt,
    ushort* __restrict__ C) {
  constexpr int M = kBS, N = kC, K = kC, nbx = 6;
  const int nwg = gridDim.x;
  const int q = nwg >> 3, rr = nwg & 7;
  const int xcd = blockIdx.x & 7, loc = blockIdx.x >> 3;
  const int vid = ((xcd < rr) ? xcd * (q + 1) : rr * (q + 1) + (xcd - rr) * q) + loc;
  const int m0 = (vid / nbx) * 128, n0 = (vid % nbx) * 128;

  __shared__ __align__(16) ushort As[128 * 32];
  __shared__ __align__(16) ushort Bs[128 * 32];
  const int tid = threadIdx.x;
  const int r0 = tid >> 2, c0 = tid & 3;
  const int r1 = r0 + 64;
  const int sc0 = (c0 ^ ((r0 >> 1) & 3)) * 8;
  const int sc1 = (c0 ^ ((r1 >> 1) & 3)) * 8;
  const int ar0 = min(m0 + r0, M - 1), ar1 = min(m0 + r1, M - 1);
  const int fq0 = (ar0 % kS) / kP, fq1 = (ar1 % kS) / kP;
  const ushort* ga0 = x4b + ((size_t)ar0 * kF + fq0) * kC + sc0;
  const ushort* ga1 = x4b + ((size_t)ar1 * kF + fq1) * kC + sc1;
  const ushort* gb0 = Bt + (size_t)(n0 + r0) * K + sc0;
  const ushort* gb1 = Bt + (size_t)(n0 + r1) * K + sc1;
  const int w = tid >> 6;
  char* lA0 = (char*)As + w * 1024;
  char* lA1 = (char*)As + 4096 + w * 1024;
  char* lB0 = (char*)Bs + w * 1024;
  char* lB1 = (char*)Bs + 4096 + w * 1024;
  const int lane = tid & 63;
  const int lr = lane & 15, lg = lane >> 4;
  const int wr = w >> 1, wc = w & 1;
  f32x4 acc[4][4] = {};
  for (int kt = 0; kt < K; kt += 32) {
    gload_lds16(ga0 + kt, lA0);
    gload_lds16(ga1 + kt, lA1);
    gload_lds16(gb0 + kt, lB0);
    gload_lds16(gb1 + kt, lB1);
    __syncthreads();
    bf16x8 af[4], bfr[4];
#pragma unroll
    for (int m = 0; m < 4; ++m) {
      int row = wr * 64 + m * 16 + lr;
      int ch = lg ^ ((row >> 1) & 3);
      af[m] = *(const bf16x8*)(As + row * 32 + ch * 8);
    }
#pragma unroll
    for (int n = 0; n < 4; ++n) {
      int row = wc * 64 + n * 16 + lr;
      int ch = lg ^ ((row >> 1) & 3);
      bfr[n] = *(const bf16x8*)(Bs + row * 32 + ch * 8);
    }
#pragma unroll
    for (int m = 0; m < 4; ++m)
#pragma unroll
      for (int n = 0; n < 4; ++n)
        acc[m][n] =
            __builtin_amdgcn_mfma_f32_16x16x32_bf16(af[m], bfr[n], acc[m][n], 0, 0, 0);
    __syncthreads();
  }
#pragma unroll
  for (int m = 0; m < 4; ++m) {
#pragma unroll
    for (int r = 0; r < 4; ++r) {
      const int mg = m0 + wr * 64 + m * 16 + lg * 4 + r;
      if (mg < M) {
        ushort* crow = C + (size_t)mg * N + n0 + wc * 64 + lr;
#pragma unroll
        for (int n = 0; n < 4; ++n) crow[n * 16] = f2bf(acc[m][n][r]);
      }
    }
  }
}

// ---------- w2[bs][h][c] = sum_d q2b[bs][h*64+d] * Wkvb[c][h*64+d] ----------
__global__ __launch_bounds__(256) void w2_gemm(
    const ushort* __restrict__ q2b, const ushort* __restrict__ Wkvb,
    ushort* __restrict__ w2b) {
  const int nwg = gridDim.x;
  const int q = nwg >> 3, rr = nwg & 7;
  const int xcd = blockIdx.x & 7, loc = blockIdx.x >> 3;
  const int vid = ((xcd < rr) ? xcd * (q + 1) : rr * (q + 1) + (xcd - rr) * q) + loc;
  const int h = vid / 150;
  const int rem = vid - h * 150;
  const int m0 = (rem / 6) * 128, n0 = (rem % 6) * 128;

  __shared__ __align__(16) ushort As[128 * 32];
  __shared__ __align__(16) ushort Bs[128 * 32];
  const int tid = threadIdx.x;
  const int r0 = tid >> 2, c0 = tid & 3;
  const int r1 = r0 + 64;
  const int sc0 = (c0 ^ ((r0 >> 1) & 3)) * 8;
  const int sc1 = (c0 ^ ((r1 >> 1) & 3)) * 8;
  const int ar0 = min(m0 + r0, kBS - 1), ar1 = min(m0 + r1, kBS - 1);
  const ushort* ga0 = q2b + (size_t)ar0 * kC + h * 64 + sc0;
  const ushort* ga1 = q2b + (size_t)ar1 * kC + h * 64 + sc1;
  const ushort* gb0 = Wkvb + (size_t)(n0 + r0) * kC + h * 64 + sc0;
  const ushort* gb1 = Wkvb + (size_t)(n0 + r1) * kC + h * 64 + sc1;
  const int w = tid >> 6;
  char* lA0 = (char*)As + w * 1024;
  char* lA1 = (char*)As + 4096 + w * 1024;
  char* lB0 = (char*)Bs + w * 1024;
  char* lB1 = (char*)Bs + 4096 + w * 1024;
  const int lane = tid & 63;
  const int lr = lane & 15, lg = lane >> 4;
  const int wr = w >> 1, wc = w & 1;
  f32x4 acc[4][4] = {};
#pragma unroll
  for (int kt = 0; kt < 64; kt += 32) {
    gload_lds16(ga0 + kt, lA0);
    gload_lds16(ga1 + kt, lA1);
    gload_lds16(gb0 + kt, lB0);
    gload_lds16(gb1 + kt, lB1);
    __syncthreads();
    bf16x8 af[4], bfr[4];
#pragma unroll
    for (int m = 0; m < 4; ++m) {
      int row = wr * 64 + m * 16 + lr;
      int ch = lg ^ ((row >> 1) & 3);
      af[m] = *(const bf16x8*)(As + row * 32 + ch * 8);
    }
#pragma unroll
    for (int n = 0; n < 4; ++n) {
      int row = wc * 64 + n * 16 + lr;
      int ch = lg ^ ((row >> 1) & 3);
      bfr[n] = *(const bf16x8*)(Bs + row * 32 + ch * 8);
    }
#pragma unroll
    for (int m = 0; m < 4; ++m)
#pragma unroll
      for (int n = 0; n < 4; ++n)
        acc[m][n] =
            __builtin_amdgcn_mfma_f32_16x16x32_bf16(af[m], bfr[n], acc[m][n], 0, 0, 0);
    __syncthreads();
  }
#pragma unroll
  for (int m = 0; m < 4; ++m) {
#pragma unroll
    for (int r = 0; r < 4; ++r) {
      const int mg = m0 + wr * 64 + m * 16 + lg * 4 + r;
      if (mg < kBS) {
        ushort* crow = w2b + (size_t)mg * (kH * kC) + h * kC + n0 + wc * 64 + lr;
#pragma unroll
        for (int n = 0; n < 4; ++n) crow[n * 16] = f2bf(acc[m][n][r]);
      }
    }
  }
}

// ---------- merged packs: x->bf16, 3 weight transposes, Wkv copy ----------
// flat grid (5810): [0,2354) pack_x | [2354,4082) Wqkv_t | [4082,4658) Wq_t |
// [4658,5234) Wproj_t | [5234,5810) Wkvb
__global__ __launch_bounds__(256) void pack_all_k(
    const float* __restrict__ x, const float* __restrict__ Wqkv,
    const float* __restrict__ Wq, const float* __restrict__ Wproj,
    const float* __restrict__ Wkv, ushort* __restrict__ xb,
    ushort* __restrict__ Wqkv_t, ushort* __restrict__ Wq_t,
    ushort* __restrict__ Wproj_t, ushort* __restrict__ Wkvb) {
  __shared__ float t[32][33];
  int bid = blockIdx.x;
  if (bid < 2354) {
    const int i = bid * 256 + threadIdx.x;
    if (i < 3138 * 768 / 4) {  // 602,496 float4s
      float4 v = ((const float4*)x)[i];
      ushort4 o = {f2bf(v.x), f2bf(v.y), f2bf(v.z), f2bf(v.w)};
      ((ushort4*)xb)[i] = o;
    }
    return;
  }
  bid -= 2354;
  if (bid < 2880) {
    const float* W;
    ushort* Wt;
    int ldw, nbw;
    float scale;
    if (bid < 1728) {
      W = Wqkv; Wt = Wqkv_t; ldw = 2304; nbw = 72; scale = 1.f;
    } else if (bid < 2304) {
      bid -= 1728;
      W = Wq; Wt = Wq_t; ldw = 768; nbw = 24; scale = kScale;
    } else {
      bid -= 2304;
      W = Wproj; Wt = Wproj_t; ldw = 768; nbw = 24; scale = 1.f;
    }
    const int nb = (bid % nbw) * 32, kb = (bid / nbw) * 32;
    const int tx = threadIdx.x & 31, ty = threadIdx.x >> 5;
#pragma unroll
    for (int i = 0; i < 32; i += 8)
      t[ty + i][tx] = W[(size_t)(kb + ty + i) * ldw + nb + tx];
    __syncthreads();
#pragma unroll
    for (int i = 0; i < 32; i += 8)
      Wt[(size_t)(nb + ty + i) * 768 + kb + tx] = f2bf(t[tx][ty + i] * scale);
    return;
  }
  bid -= 2880;
  const int i = bid * 256 + threadIdx.x;  // < 576*256 == 768*192 exactly
  const int c = i / 192, j4 = i - c * 192;
  float4 v = *(const float4*)(Wkv + (size_t)c * 1536 + j4 * 4);
  ushort4 o = {f2bf(v.x), f2bf(v.y), f2bf(v.z), f2bf(v.w)};
  *(ushort4*)(Wkvb + (size_t)c * 768 + j4 * 4) = o;
}

// ---------- pack V transposed: Vt[bh*8+f][64][224] bf16 (coalesced) ----------
__global__ void pack_vt_k(const ushort* __restrict__ qkvb,
                          ushort* __restrict__ Vt) {
  const int idx = blockIdx.x * 256 + threadIdx.x;
  if (idx >= kBH * kF * kD * kPpad) return;
  const int n = idx % kPpad;
  const int j = (idx / kPpad) & 63;
  const int f = (idx / (kPpad * kD)) & 7;
  const int bh = idx / (kPpad * kD * kF);
  const int b = bh / kH, h = bh % kH;
  ushort v = 0;
  if (n < kP)
    v = qkvb[(size_t)(b * kN + 1 + f * kP + n) * k3C + 2 * kC + h * kD + j];
  Vt[idx] = v;
}

// ---------- spatial attention, swapped-QK^T, LDS-free (r9 proven config) ----
__global__ __launch_bounds__(256) void sp_attn_mfma(
    const ushort* __restrict__ Qb, const ushort* __restrict__ Kb,
    const ushort* __restrict__ Vt, ushort* __restrict__ x4b) {
  const int w = threadIdx.x >> 6;
  const int lane = threadIdx.x & 63;
  const int fbh = blockIdx.x;
  const int f = fbh / 24, bh = fbh % 24;
  const int tile = blockIdx.y * 4 + w;  // 0..48 valid
  if (tile >= 49) return;
  const int q0 = tile * 32;
  const int lr = lane & 15;
  const int lg = lane >> 4;

  const ushort* qrow = Qb + ((size_t)bh * kS + q0 + lr) * kD + lg * 8;
  const bf16x8 a00 = *(const bf16x8*)qrow;
  const bf16x8 a01 = *(const bf16x8*)(qrow + 32);
  const bf16x8 a10 = *(const bf16x8*)(qrow + 16 * kD);
  const bf16x8 a11 = *(const bf16x8*)(qrow + 16 * kD + 32);

  f32x4 s0[13], s1[13];
  const ushort* kbase = Kb + ((size_t)bh * kS + f * kP + lr) * kD + lg * 8;
#pragma unroll
  for (int nt = 0; nt < 13; ++nt) {
    const ushort* kr = kbase + (size_t)nt * 16 * kD;
    bf16x8 b0 = *(const bf16x8*)kr;
    bf16x8 b1 = *(const bf16x8*)(kr + 32);
    f32x4 acc0 = {0.f, 0.f, 0.f, 0.f}, acc1 = {0.f, 0.f, 0.f, 0.f};
    acc0 = __builtin_amdgcn_mfma_f32_16x16x32_bf16(b0, a00, acc0, 0, 0, 0);
    acc0 = __builtin_amdgcn_mfma_f32_16x16x32_bf16(b1, a01, acc0, 0, 0, 0);
    acc1 = __builtin_amdgcn_mfma_f32_16x16x32_bf16(b0, a10, acc1, 0, 0, 0);
    acc1 = __builtin_amdgcn_mfma_f32_16x16x32_bf16(b1, a11, acc1, 0, 0, 0);
    s0[nt] = acc0;
    s1[nt] = acc1;
  }
  if (lg >= 1) {
#pragma unroll
    for (int r = 0; r < 4; ++r) { s0[12][r] = -1e30f; s1[12][r] = -1e30f; }
  }

  float m0 = -1e30f, m1 = -1e30f;
#pragma unroll
  for (int nt = 0; nt < 13; ++nt)
#pragma unroll
    for (int r = 0; r < 4; ++r) {
      m0 = fmaxf(m0, s0[nt][r]);
      m1 = fmaxf(m1, s1[nt][r]);
    }
  m0 = fmaxf(m0, __shfl_xor(m0, 16));
  m0 = fmaxf(m0, __shfl_xor(m0, 32));
  m1 = fmaxf(m1, __shfl_xor(m1, 16));
  m1 = fmaxf(m1, __shfl_xor(m1, 32));

  float sum0 = 0.f, sum1 = 0.f;
  u32x4 breg0[7], breg1[7];
#pragma unroll
  for (int blk = 0; blk < 7; ++blk) {
    unsigned pk0[2][2], pk1[2][2];
#pragma unroll
    for (int t = 0; t < 2; ++t) {
      const int nt = blk * 2 + t;
      if (nt < 13) {
        float e0 = __expf(s0[nt][0] - m0), e1 = __expf(s0[nt][1] - m0);
        float e2 = __expf(s0[nt][2] - m0), e3 = __expf(s0[nt][3] - m0);
        sum0 += (e0 + e1) + (e2 + e3);
        pk0[t][0] = ((unsigned)f2bf(e1) << 16) | f2bf(e0);
        pk0[t][1] = ((unsigned)f2bf(e3) << 16) | f2bf(e2);
        float g0 = __expf(s1[nt][0] - m1), g1 = __expf(s1[nt][1] - m1);
        float g2 = __expf(s1[nt][2] - m1), g3 = __expf(s1[nt][3] - m1);
        sum1 += (g0 + g1) + (g2 + g3);
        pk1[t][0] = ((unsigned)f2bf(g1) << 16) | f2bf(g0);
        pk1[t][1] = ((unsigned)f2bf(g3) << 16) | f2bf(g2);
      } else {
        pk0[t][0] = 0; pk0[t][1] = 0;
        pk1[t][0] = 0; pk1[t][1] = 0;
      }
    }
#pragma unroll
    for (int j2 = 0; j2 < 4; ++j2) {
      const int srcLane = ((lg & 1) * 2 + (j2 >> 1)) * 16 + lr;
      unsigned t0 = (unsigned)__shfl((int)pk0[0][j2 & 1], srcLane);
      unsigned t1 = (unsigned)__shfl((int)pk0[1][j2 & 1], srcLane);
      breg0[blk][j2] = (lg < 2) ? t0 : t1;
      unsigned u0 = (unsigned)__shfl((int)pk1[0][j2 & 1], srcLane);
      unsigned u1 = (unsigned)__shfl((int)pk1[1][j2 & 1], srcLane);
      breg1[blk][j2] = (lg < 2) ? u0 : u1;
    }
  }
  sum0 += __shfl_xor(sum0, 16);
  sum0 += __shfl_xor(sum0, 32);
  sum1 += __shfl_xor(sum1, 16);
  sum1 += __shfl_xor(sum1, 32);
  const float inv0 = 1.f / sum0, inv1 = 1.f / sum1;

  const ushort* vbase = Vt + ((size_t)(bh * kF + f) * kD + lr) * kPpad + lg * 8;
  f32x4 o0[4] = {}, o1[4] = {};
#pragma unroll
  for (int nt2 = 0; nt2 < 4; ++nt2) {
    const ushort* vb = vbase + (size_t)nt2 * 16 * kPpad;
#pragma unroll
    for (int blk = 0; blk < 7; ++blk) {
      bf16x8 av = *(const bf16x8*)(vb + blk * 32);
      bf16x8 pb0 = __builtin_bit_cast(bf16x8, breg0[blk]);
      bf16x8 pb1 = __builtin_bit_cast(bf16x8, breg1[blk]);
      o0[nt2] = __builtin_amdgcn_mfma_f32_16x16x32_bf16(av, pb0, o0[nt2], 0, 0, 0);
      o1[nt2] = __builtin_amdgcn_mfma_f32_16x16x32_bf16(av, pb1, o1[nt2], 0, 0, 0);
    }
  }

  const int b = bh / kH, h = bh % kH;
  const size_t base0 =
      ((size_t)(b * kS + q0 + lr) * kF + f) * kC + h * kD + lg * 4;
#pragma unroll
  for (int nt2 = 0; nt2 < 4; ++nt2) {
    ushort4 v0, v1;
    v0.x = f2bf(o0[nt2][0] * inv0);
    v0.y = f2bf(o0[nt2][1] * inv0);
    v0.z = f2bf(o0[nt2][2] * inv0);
    v0.w = f2bf(o0[nt2][3] * inv0);
    *(ushort4*)(x4b + base0 + nt2 * 16) = v0;
    v1.x = f2bf(o1[nt2][0] * inv1);
    v1.y = f2bf(o1[nt2][1] * inv1);
    v1.z = f2bf(o1[nt2][2] * inv1);
    v1.w = f2bf(o1[nt2][3] * inv1);
    *(ushort4*)(x4b + base0 + (size_t)16 * kF * kC + nt2 * 16) = v1;
  }
}

// ---------- cls attention, 4-phase parallel (bf16 qkv) ----------
__global__ __launch_bounds__(256) void cls_logits_k(const ushort* __restrict__ qkvb,
                                                    float* __restrict__ logits) {
  const int chunk = blockIdx.x, bh = blockIdx.y;
  const int b = bh / kH, h = bh % kH;
  const int g = threadIdx.x & 15, row = threadIdx.x >> 4;
  const size_t base = (size_t)b * kN * k3C;
  const ushort* qp = qkvb + base + h * kD + g * 4;
  const float q0 = bf2f(qp[0]) * kScale, q1 = bf2f(qp[1]) * kScale;
  const float q2 = bf2f(qp[2]) * kScale, q3 = bf2f(qp[3]) * kScale;
#pragma unroll
  for (int i = 0; i < 16; ++i) {
    const int n = chunk * 256 + i * 16 + row;
    if (n < kN) {
      ushort4 kv =
          *(const ushort4*)(qkvb + base + (size_t)n * k3C + kC + h * kD + g * 4);
      float p = q0 * bf2f(kv.x) + q1 * bf2f(kv.y) + q2 * bf2f(kv.z) +
                q3 * bf2f(kv.w);
#pragma unroll
      for (int o = 8; o; o >>= 1) p += __shfl_xor(p, o, 16);
      if (g == 0) logits[bh * kLpad + n] = p;
    }
  }
}

__global__ __launch_bounds__(256) void cls_softmax_k(const float* __restrict__ logits,
                                                     float* __restrict__ pbuf) {
  __shared__ float red[8];
  const int bh = blockIdx.x, tid = threadIdx.x;
  float m = -1e30f;
  for (int n = tid; n < kN; n += 256) m = fmaxf(m, logits[bh * kLpad + n]);
#pragma unroll
  for (int o = 32; o; o >>= 1) m = fmaxf(m, __shfl_xor(m, o));
  if ((tid & 63) == 0) red[tid >> 6] = m;
  __syncthreads();
  m = fmaxf(fmaxf(red[0], red[1]), fmaxf(red[2], red[3]));
  float sum = 0.f;
  for (int n = tid; n < kN; n += 256) sum += __expf(logits[bh * kLpad + n] - m);
#pragma unroll
  for (int o = 32; o; o >>= 1) sum += __shfl_xor(sum, o);
  if ((tid & 63) == 0) red[4 + (tid >> 6)] = sum;
  __syncthreads();
  const float inv = 1.f / (red[4] + red[5] + red[6] + red[7]);
  for (int n = tid; n < kN; n += 256)
    pbuf[bh * kLpad + n] = __expf(logits[bh * kLpad + n] - m) * inv;
}

__global__ __launch_bounds__(256) void cls_pv_k(const ushort* __restrict__ qkvb,
                                                const float* __restrict__ pbuf,
                                                float* __restrict__ partial) {
  __shared__ float pb[256];
  const int chunk = blockIdx.x, bh = blockIdx.y;
  const int b = bh / kH, h = bh % kH;
  const int j = threadIdx.x & 63, part = threadIdx.x >> 6;
  const size_t base = (size_t)b * kN * k3C + 2 * kC + h * kD + j;
  float acc = 0.f;
#pragma unroll 4
  for (int i = 0; i < 64; ++i) {
    const int n = chunk * 256 + i * 4 + part;
    if (n < kN)
      acc = fmaf(pbuf[bh * kLpad + n], bf2f(qkvb[base + (size_t)n * k3C]), acc);
  }
  pb[threadIdx.x] = acc;
  __syncthreads();
  if (part == 0)
    partial[((size_t)bh * 7 + chunk) * kD + j] =
        pb[j] + pb[64 + j] + pb[128 + j] + pb[192 + j];
}

__global__ void cls_red_k(const float* __restrict__ partial,
                          ushort* __restrict__ xin_b) {
  const int bh = blockIdx.x, j = threadIdx.x;
  const int b = bh / kH, h = bh % kH;
  float s = 0.f;
#pragma unroll
  for (int c = 0; c < 7; ++c) s += partial[((size_t)bh * 7 + c) * kD + j];
  xin_b[(size_t)(b * kN) * kC + h * kD + j] = f2bf(s);
}

// ---------- fused temporal attention: one block per (b,s) ----------
__global__ __launch_bounds__(256) void attn2_fused(
    const ushort* __restrict__ x4b, const ushort* __restrict__ w2b,
    ushort* __restrict__ xin_b, float* __restrict__ attn2out) {
  __shared__ __align__(16) ushort x4s[kF * kC];
  __shared__ __align__(16) ushort w2s[kH * kC];
  const int bs = blockIdx.x;
  const int b = bs / kS, s = bs - b * kS;
  const int tid = threadIdx.x;
  {
    const ulonglong2* src = (const ulonglong2*)(x4b + (size_t)bs * kF * kC);
    ulonglong2* dst = (ulonglong2*)x4s;
    for (int i = tid; i < kF * kC / 8; i += 256) dst[i] = src[i];
    const ulonglong2* srcw = (const ulonglong2*)(w2b + (size_t)bs * kH * kC);
    ulonglong2* dstw = (ulonglong2*)w2s;
    for (int i = tid; i < kH * kC / 8; i += 256) dstw[i] = srcw[i];
  }
  __syncthreads();
  const int w = tid >> 6, lane = tid & 63;
#pragma unroll
  for (int hh = 0; hh < 3; ++hh) {
    const int h = w * 3 + hh;
    float part[kF] = {};
#pragma unroll
    for (int i = 0; i < 3; ++i) {
      const int c = lane * 4 + i * 256;
      ushort4 wv = *(const ushort4*)&w2s[h * kC + c];
      const float w0 = bf2f(wv.x), w1 = bf2f(wv.y);
      const float w2v = bf2f(wv.z), w3 = bf2f(wv.w);
#pragma unroll
      for (int f = 0; f < kF; ++f) {
        ushort4 xv = *(const ushort4*)&x4s[f * kC + c];
        part[f] += bf2f(xv.x) * w0 + bf2f(xv.y) * w1 + bf2f(xv.z) * w2v +
                   bf2f(xv.w) * w3;
      }
    }
    float l[kF];
#pragma unroll
    for (int f = 0; f < kF; ++f) {
      float p = part[f];
#pragma unroll
      for (int o = 32; o; o >>= 1) p += __shfl_xor(p, o);
      l[f] = p;
    }
    float m = l[0];
#pragma unroll
    for (int f = 1; f < kF; ++f) m = fmaxf(m, l[f]);
    float sum = 0.f;
#pragma unroll
    for (int f = 0; f < kF; ++f) {
      l[f] = __expf(l[f] - m);
      sum += l[f];
    }
    const float inv = 1.f / sum;
    float pv = 0.f;
#pragma unroll
    for (int f = 0; f < kF; ++f) pv = (lane == f) ? l[f] : pv;
    if (lane < kF)
      attn2out[((size_t)(b * kH + h) * kS + s) * kF + lane] = pv * inv;
    float o = 0.f;
#pragma unroll
    for (int f = 0; f < kF; ++f)
      o = fmaf(l[f] * inv, bf2f(x4s[f * kC + h * kD + lane]), o);
    xin_b[(size_t)(b * kN + 1 + s) * kC + h * kD + lane] = f2bf(o);
  }
}

extern "C" void kernel_launch(void* const* d_in, const int* in_sizes, int n_in,
                              void* d_out, int out_size, void* d_ws,
                              size_t ws_size, hipStream_t stream) {
  const float* x = (const float*)d_in[0];
  const float* Wqkv = (const float*)d_in[1];
  const float* Wq = (const float*)d_in[2];
  const float* Wkv = (const float*)d_in[3];
  const float* Wproj = (const float*)d_in[4];
  const float* bproj = (const float*)d_in[5];

  char* p = (char*)d_ws;
  ushort* qkvb = (ushort*)p;         p += (size_t)3138 * 2304 * 2;
  ushort* w2b = (ushort*)p;          p += (size_t)kBS * kH * kC * 2;
  ushort* q2b = (ushort*)p;          p += (size_t)kBS * kC * 2;
  ushort* x4b = (ushort*)p;          p += (size_t)25088 * 768 * 2;
  ushort* xin_b = (ushort*)p;        p += (size_t)3138 * 768 * 2;
  ushort* xb = (ushort*)p;           p += (size_t)3138 * 768 * 2;
  ushort* Wqkv_t = (ushort*)p;       p += (size_t)2304 * 768 * 2;
  ushort* Wq_t = (ushort*)p;         p += (size_t)768 * 768 * 2;
  ushort* Wkvb = (ushort*)p;         p += (size_t)768 * 768 * 2;
  ushort* Wproj_t = (ushort*)p;      p += (size_t)768 * 768 * 2;
  ushort* Qb = (ushort*)p;           p += (size_t)kBH * kS * kD * 2;
  ushort* Kb = (ushort*)p;           p += ((size_t)kBH * kS + 16) * kD * 2;
  ushort* Vt = (ushort*)p;           p += (size_t)kBH * kF * kD * kPpad * 2;
  float* clsL = (float*)p;           p += (size_t)kBH * kLpad * 4;
  float* clsP = (float*)p;           p += (size_t)kBH * kLpad * 4;
  float* clsPart = (float*)p;

  float* out = (float*)d_out;
  float* attn2 = out + (size_t)kB * kN * kC;

  // 0. merged packs (x + 4 weights); grid 5810 = 2354 + 2880 + 576
  pack_all_k<<<5810, 256, 0, stream>>>(x, Wqkv, Wq, Wproj, Wkv, xb, Wqkv_t,
                                       Wq_t, Wproj_t, Wkvb);
  // 1. qkv GEMM with fused Qb/Kb pack -> qkvb, Qb, Kb
  gemm_qkv<<<18 * 25, 256, 0, stream>>>(xb, Wqkv_t, qkvb, Qb, Kb);
  // 2. Vt pack (coalesced)
  pack_vt_k<<<(kBH * kF * kD * kPpad + 255) / 256, 256, 0, stream>>>(qkvb, Vt);
  // 3. cls attention (4-phase)
  cls_logits_k<<<dim3(7, 24), 256, 0, stream>>>(qkvb, clsL);
  cls_softmax_k<<<24, 256, 0, stream>>>(clsL, clsP);
  cls_pv_k<<<dim3(7, 24), 256, 0, stream>>>(qkvb, clsP, clsPart);
  cls_red_k<<<24, 64, 0, stream>>>(clsPart, xin_b);
  // 4. spatial attention -> x4b (r9 config: 4 waves, no setprio — r13 A/B
  //    showed setprio is a ~5us regression here: lockstep waves, cf. m190)
  sp_attn_mfma<<<dim3(192, 13), 256, 0, stream>>>(Qb, Kb, Vt, x4b);
  // 5. q2 = diag(x4) @ (Wq*scale)  (fused xd gather)
  gemm_q2<<<6 * 25, 256, 0, stream>>>(x4b, Wq_t, q2b);
  // 6. w2[bs,h,:] = Wkv_h^T @ q2[bs,h,:]
  w2_gemm<<<1800, 256, 0, stream>>>(q2b, Wkvb, w2b);
  // 7. fused temporal attention
  attn2_fused<<<kBS, 256, 0, stream>>>(x4b, w2b, xin_b, attn2);
  // 8. out = xin @ Wproj + bproj
  gemm_bf16<float><<<6 * 25, 256, 0, stream>>>(xin_b, Wproj_t, bproj, out, 3138,
                                               768, 768, 6);
}

// Round 15
// 244.612 us; speedup vs baseline: 1.0427x; 1.0166x over previous
//
#include <hip/hip_runtime.h>

namespace {
constexpr int kB = 2;
constexpr int kH = 12;
constexpr int kD = 64;
constexpr int kC = 768;
constexpr int kF = 8;
constexpr int kP = 196;
constexpr int kS = kF * kP;      // 1568
constexpr int kN = 1 + kS;       // 1569
constexpr int k3C = 3 * kC;      // 2304
constexpr float kScale = 0.125f; // d^-0.5 (exact power of 2)
constexpr int kBH = kB * kH;     // 24
constexpr int kPpad = 224;       // keys padded (max touched key-offset 223)
constexpr int kLpad = 1600;      // cls logits row stride
constexpr int kBS = kB * kS;     // 3136
}

typedef __attribute__((ext_vector_type(8))) short bf16x8;
typedef __attribute__((ext_vector_type(8))) unsigned short u16x8;
typedef __attribute__((ext_vector_type(4))) float f32x4;
typedef __attribute__((ext_vector_type(4))) unsigned int u32x4;

__device__ inline ushort f2bf(float x) {
  union { float f; unsigned u; } v{x};
  unsigned r = v.u + 0x7fff + ((v.u >> 16) & 1);
  return (ushort)(r >> 16);
}
__device__ inline float bf2f(ushort u) {
  union { unsigned u; float f; } v{(unsigned)u << 16};
  return v.f;
}

__device__ __forceinline__ void gload_lds16(const void* g, void* l) {
  __builtin_amdgcn_global_load_lds(
      (const __attribute__((address_space(1))) unsigned int*)g,
      (__attribute__((address_space(3))) unsigned int*)l, 16, 0, 0);
}

__device__ inline void storeC(float v, float* p) { *p = v; }
__device__ inline void storeC(float v, ushort* p) { *p = f2bf(v); }

// ---------- bf16 MFMA GEMM: C[M,N] = A[M,K]bf16 @ Bt[N,K]bf16^T (+bias) ----
template <typename OutT>
__global__ __launch_bounds__(256) void gemm_bf16(
    const ushort* __restrict__ A, const ushort* __restrict__ Bt,
    const float* __restrict__ bias, OutT* __restrict__ C,
    int M, int N, int K, int nbx) {
  const int nwg = gridDim.x;
  const int q = nwg >> 3, rr = nwg & 7;
  const int xcd = blockIdx.x & 7, loc = blockIdx.x >> 3;
  const int vid = ((xcd < rr) ? xcd * (q + 1) : rr * (q + 1) + (xcd - rr) * q) + loc;
  const int m0 = (vid / nbx) * 128, n0 = (vid % nbx) * 128;

  __shared__ __align__(16) ushort As[128 * 32];
  __shared__ __align__(16) ushort Bs[128 * 32];
  const int tid = threadIdx.x;
  const int r0 = tid >> 2, c0 = tid & 3;
  const int r1 = r0 + 64;
  const int sc0 = (c0 ^ ((r0 >> 1) & 3)) * 8;
  const int sc1 = (c0 ^ ((r1 >> 1) & 3)) * 8;
  const int ar0 = min(m0 + r0, M - 1), ar1 = min(m0 + r1, M - 1);
  const ushort* ga0 = A + (size_t)ar0 * K + sc0;
  const ushort* ga1 = A + (size_t)ar1 * K + sc1;
  const ushort* gb0 = Bt + (size_t)(n0 + r0) * K + sc0;
  const ushort* gb1 = Bt + (size_t)(n0 + r1) * K + sc1;
  const int w = tid >> 6;
  char* lA0 = (char*)As + w * 1024;
  char* lA1 = (char*)As + 4096 + w * 1024;
  char* lB0 = (char*)Bs + w * 1024;
  char* lB1 = (char*)Bs + 4096 + w * 1024;
  const int lane = tid & 63;
  const int lr = lane & 15, lg = lane >> 4;
  const int wr = w >> 1, wc = w & 1;
  f32x4 acc[4][4] = {};
  for (int kt = 0; kt < K; kt += 32) {
    gload_lds16(ga0 + kt, lA0);
    gload_lds16(ga1 + kt, lA1);
    gload_lds16(gb0 + kt, lB0);
    gload_lds16(gb1 + kt, lB1);
    __syncthreads();
    bf16x8 af[4], bfr[4];
#pragma unroll
    for (int m = 0; m < 4; ++m) {
      int row = wr * 64 + m * 16 + lr;
      int ch = lg ^ ((row >> 1) & 3);
      af[m] = *(const bf16x8*)(As + row * 32 + ch * 8);
    }
#pragma unroll
    for (int n = 0; n < 4; ++n) {
      int row = wc * 64 + n * 16 + lr;
      int ch = lg ^ ((row >> 1) & 3);
      bfr[n] = *(const bf16x8*)(Bs + row * 32 + ch * 8);
    }
#pragma unroll
    for (int m = 0; m < 4; ++m)
#pragma unroll
      for (int n = 0; n < 4; ++n)
        acc[m][n] =
            __builtin_amdgcn_mfma_f32_16x16x32_bf16(af[m], bfr[n], acc[m][n], 0, 0, 0);
    __syncthreads();
  }
#pragma unroll
  for (int m = 0; m < 4; ++m) {
#pragma unroll
    for (int r = 0; r < 4; ++r) {
      const int mg = m0 + wr * 64 + m * 16 + lg * 4 + r;
      if (mg < M) {
        OutT* crow = C + (size_t)mg * N + n0 + wc * 64 + lr;
#pragma unroll
        for (int n = 0; n < 4; ++n) {
          float v = acc[m][n][r];
          if (bias) v += bias[n0 + wc * 64 + n * 16 + lr];
          storeC(v, crow + n * 16);
        }
      }
    }
  }
}

// ---------- qkv GEMM with fused Qb/Kb pack epilogue (coalesced only) ----------
__global__ __launch_bounds__(256) void gemm_qkv(
    const ushort* __restrict__ A, const ushort* __restrict__ Bt,
    ushort* __restrict__ qkvb, ushort* __restrict__ Qb,
    ushort* __restrict__ Kb) {
  constexpr int M = 3138, N = k3C, K = kC, nbx = 18;
  const int nwg = gridDim.x;
  const int q = nwg >> 3, rr = nwg & 7;
  const int xcd = blockIdx.x & 7, loc = blockIdx.x >> 3;
  const int vid = ((xcd < rr) ? xcd * (q + 1) : rr * (q + 1) + (xcd - rr) * q) + loc;
  const int m0 = (vid / nbx) * 128, n0 = (vid % nbx) * 128;

  __shared__ __align__(16) ushort As[128 * 32];
  __shared__ __align__(16) ushort Bs[128 * 32];
  const int tid = threadIdx.x;
  const int r0 = tid >> 2, c0 = tid & 3;
  const int r1 = r0 + 64;
  const int sc0 = (c0 ^ ((r0 >> 1) & 3)) * 8;
  const int sc1 = (c0 ^ ((r1 >> 1) & 3)) * 8;
  const int ar0 = min(m0 + r0, M - 1), ar1 = min(m0 + r1, M - 1);
  const ushort* ga0 = A + (size_t)ar0 * K + sc0;
  const ushort* ga1 = A + (size_t)ar1 * K + sc1;
  const ushort* gb0 = Bt + (size_t)(n0 + r0) * K + sc0;
  const ushort* gb1 = Bt + (size_t)(n0 + r1) * K + sc1;
  const int w = tid >> 6;
  char* lA0 = (char*)As + w * 1024;
  char* lA1 = (char*)As + 4096 + w * 1024;
  char* lB0 = (char*)Bs + w * 1024;
  char* lB1 = (char*)Bs + 4096 + w * 1024;
  const int lane = tid & 63;
  const int lr = lane & 15, lg = lane >> 4;
  const int wr = w >> 1, wc = w & 1;
  f32x4 acc[4][4] = {};
  for (int kt = 0; kt < K; kt += 32) {
    gload_lds16(ga0 + kt, lA0);
    gload_lds16(ga1 + kt, lA1);
    gload_lds16(gb0 + kt, lB0);
    gload_lds16(gb1 + kt, lB1);
    __syncthreads();
    bf16x8 af[4], bfr[4];
#pragma unroll
    for (int m = 0; m < 4; ++m) {
      int row = wr * 64 + m * 16 + lr;
      int ch = lg ^ ((row >> 1) & 3);
      af[m] = *(const bf16x8*)(As + row * 32 + ch * 8);
    }
#pragma unroll
    for (int n = 0; n < 4; ++n) {
      int row = wc * 64 + n * 16 + lr;
      int ch = lg ^ ((row >> 1) & 3);
      bfr[n] = *(const bf16x8*)(Bs + row * 32 + ch * 8);
    }
#pragma unroll
    for (int m = 0; m < 4; ++m)
#pragma unroll
      for (int n = 0; n < 4; ++n)
        acc[m][n] =
            __builtin_amdgcn_mfma_f32_16x16x32_bf16(af[m], bfr[n], acc[m][n], 0, 0, 0);
    __syncthreads();
  }
#pragma unroll
  for (int m = 0; m < 4; ++m) {
#pragma unroll
    for (int r = 0; r < 4; ++r) {
      const int mg = m0 + wr * 64 + m * 16 + lg * 4 + r;
      if (mg >= M) continue;
      const int b = (mg >= kN) ? 1 : 0;
      const int tok = mg - b * kN;
      ushort* qrow = qkvb + (size_t)mg * k3C + n0 + wc * 64 + lr;
#pragma unroll
      for (int n = 0; n < 4; ++n) {
        const int col = n0 + wc * 64 + n * 16 + lr;
        const float v = acc[m][n][r];
        const ushort bv = f2bf(v);
        qrow[n * 16] = bv;
        if (tok >= 1) {
          const int s = tok - 1;
          const int sec = col / kC;
          const int cj = col - sec * kC;
          const int h = cj >> 6, j = cj & 63;
          const int bh = b * kH + h;
          if (sec == 0) {
            Qb[((size_t)bh * kS + s) * kD + j] = f2bf(v * kScale);
          } else if (sec == 1) {
            Kb[((size_t)bh * kS + s) * kD + j] = bv;
          }
        }
      }
    }
  }
}

// ---------- q2 GEMM with fused xd gather: A-row = x4b diagonal ----------
__global__ __launch_bounds__(256) void gemm_q2(
    const ushort* __restrict__ x4b, const ushort* __restrict__ Bt,
    ushort* __restrict__ C) {
  constexpr int M = kBS, N = kC, K = kC, nbx = 6;
  const int nwg = gridDim.x;
  const int q = nwg >> 3, rr = nwg & 7;
  const int xcd = blockIdx.x & 7, loc = blockIdx.x >> 3;
  const int vid = ((xcd < rr) ? xcd * (q + 1) : rr * (q + 1) + (xcd - rr) * q) + loc;
  const int m0 = (vid / nbx) * 128, n0 = (vid % nbx) * 128;

  __shared__ __align__(16) ushort As[128 * 32];
  __shared__ __align__(16) ushort Bs[128 * 32];
  const int tid = threadIdx.x;
  const int r0 = tid >> 2, c0 = tid & 3;
  const int r1 = r0 + 64;
  const int sc0 = (c0 ^ ((r0 >> 1) & 3)) * 8;
  const int sc1 = (c0 ^ ((r1 >> 1) & 3)) * 8;
  const int ar0 = min(m0 + r0, M - 1), ar1 = min(m0 + r1, M - 1);
  const int fq0 = (ar0 % kS) / kP, fq1 = (ar1 % kS) / kP;
  const ushort* ga0 = x4b + ((size_t)ar0 * kF + fq0) * kC + sc0;
  const ushort* ga1 = x4b + ((size_t)ar1 * kF + fq1) * kC + sc1;
  const ushort* gb0 = Bt + (size_t)(n0 + r0) * K + sc0;
  const ushort* gb1 = Bt + (size_t)(n0 + r1) * K + sc1;
  const int w = tid >> 6;
  char* lA0 = (char*)As + w * 1024;
  char* lA1 = (char*)As + 4096 + w * 1024;
  char* lB0 = (char*)Bs + w * 1024;
  char* lB1 = (char*)Bs + 4096 + w * 1024;
  const int lane = tid & 63;
  const int lr = lane & 15, lg = lane >> 4;
  const int wr = w >> 1, wc = w & 1;
  f32x4 acc[4][4] = {};
  for (int kt = 0; kt < K; kt += 32) {
    gload_lds16(ga0 + kt, lA0);
    gload_lds16(ga1 + kt, lA1);
    gload_lds16(gb0 + kt, lB0);
    gload_lds16(gb1 + kt, lB1);
    __syncthreads();
    bf16x8 af[4], bfr[4];
#pragma unroll
    for (int m = 0; m < 4; ++m) {
      int row = wr * 64 + m * 16 + lr;
      int ch = lg ^ ((row >> 1) & 3);
      af[m] = *(const bf16x8*)(As + row * 32 + ch * 8);
    }
#pragma unroll
    for (int n = 0; n < 4; ++n) {
      int row = wc * 64 + n * 16 + lr;
      int ch = lg ^ ((row >> 1) & 3);
      bfr[n] = *(const bf16x8*)(Bs + row * 32 + ch * 8);
    }
#pragma unroll
    for (int m = 0; m < 4; ++m)
#pragma unroll
      for (int n = 0; n < 4; ++n)
        acc[m][n] =
            __builtin_amdgcn_mfma_f32_16x16x32_bf16(af[m], bfr[n], acc[m][n], 0, 0, 0);
    __syncthreads();
  }
#pragma unroll
  for (int m = 0; m < 4; ++m) {
#pragma unroll
    for (int r = 0; r < 4; ++r) {
      const int mg = m0 + wr * 64 + m * 16 + lg * 4 + r;
      if (mg < M) {
        ushort* crow = C + (size_t)mg * N + n0 + wc * 64 + lr;
#pragma unroll
        for (int n = 0; n < 4; ++n) crow[n * 16] = f2bf(acc[m][n][r]);
      }
    }
  }
}

// ---------- w2[bs][h][c] = sum_d q2b[bs][h*64+d] * Wkvb[c][h*64+d] ----------
__global__ __launch_bounds__(256) void w2_gemm(
    const ushort* __restrict__ q2b, const ushort* __restrict__ Wkvb,
    ushort* __restrict__ w2b) {
  const int nwg = gridDim.x;
  const int q = nwg >> 3, rr = nwg & 7;
  const int xcd = blockIdx.x & 7, loc = blockIdx.x >> 3;
  const int vid = ((xcd < rr) ? xcd * (q + 1) : rr * (q + 1) + (xcd - rr) * q) + loc;
  const int h = vid / 150;
  const int rem = vid - h * 150;
  const int m0 = (rem / 6) * 128, n0 = (rem % 6) * 128;

  __shared__ __align__(16) ushort As[128 * 32];
  __shared__ __align__(16) ushort Bs[128 * 32];
  const int tid = threadIdx.x;
  const int r0 = tid >> 2, c0 = tid & 3;
  const int r1 = r0 + 64;
  const int sc0 = (c0 ^ ((r0 >> 1) & 3)) * 8;
  const int sc1 = (c0 ^ ((r1 >> 1) & 3)) * 8;
  const int ar0 = min(m0 + r0, kBS - 1), ar1 = min(m0 + r1, kBS - 1);
  const ushort* ga0 = q2b + (size_t)ar0 * kC + h * 64 + sc0;
  const ushort* ga1 = q2b + (size_t)ar1 * kC + h * 64 + sc1;
  const ushort* gb0 = Wkvb + (size_t)(n0 + r0) * kC + h * 64 + sc0;
  const ushort* gb1 = Wkvb + (size_t)(n0 + r1) * kC + h * 64 + sc1;
  const int w = tid >> 6;
  char* lA0 = (char*)As + w * 1024;
  char* lA1 = (char*)As + 4096 + w * 1024;
  char* lB0 = (char*)Bs + w * 1024;
  char* lB1 = (char*)Bs + 4096 + w * 1024;
  const int lane = tid & 63;
  const int lr = lane & 15, lg = lane >> 4;
  const int wr = w >> 1, wc = w & 1;
  f32x4 acc[4][4] = {};
#pragma unroll
  for (int kt = 0; kt < 64; kt += 32) {
    gload_lds16(ga0 + kt, lA0);
    gload_lds16(ga1 + kt, lA1);
    gload_lds16(gb0 + kt, lB0);
    gload_lds16(gb1 + kt, lB1);
    __syncthreads();
    bf16x8 af[4], bfr[4];
#pragma unroll
    for (int m = 0; m < 4; ++m) {
      int row = wr * 64 + m * 16 + lr;
      int ch = lg ^ ((row >> 1) & 3);
      af[m] = *(const bf16x8*)(As + row * 32 + ch * 8);
    }
#pragma unroll
    for (int n = 0; n < 4; ++n) {
      int row = wc * 64 + n * 16 + lr;
      int ch = lg ^ ((row >> 1) & 3);
      bfr[n] = *(const bf16x8*)(Bs + row * 32 + ch * 8);
    }
#pragma unroll
    for (int m = 0; m < 4; ++m)
#pragma unroll
      for (int n = 0; n < 4; ++n)
        acc[m][n] =
            __builtin_amdgcn_mfma_f32_16x16x32_bf16(af[m], bfr[n], acc[m][n], 0, 0, 0);
    __syncthreads();
  }
#pragma unroll
  for (int m = 0; m < 4; ++m) {
#pragma unroll
    for (int r = 0; r < 4; ++r) {
      const int mg = m0 + wr * 64 + m * 16 + lg * 4 + r;
      if (mg < kBS) {
        ushort* crow = w2b + (size_t)mg * (kH * kC) + h * kC + n0 + wc * 64 + lr;
#pragma unroll
        for (int n = 0; n < 4; ++n) crow[n * 16] = f2bf(acc[m][n][r]);
      }
    }
  }
}

// ---------- merged packs: x->bf16, 3 weight transposes, Wkv copy ----------
// flat grid (5810): [0,2354) pack_x | [2354,4082) Wqkv_t | [4082,4658) Wq_t |
// [4658,5234) Wproj_t | [5234,5810) Wkvb
__global__ __launch_bounds__(256) void pack_all_k(
    const float* __restrict__ x, const float* __restrict__ Wqkv,
    const float* __restrict__ Wq, const float* __restrict__ Wproj,
    const float* __restrict__ Wkv, ushort* __restrict__ xb,
    ushort* __restrict__ Wqkv_t, ushort* __restrict__ Wq_t,
    ushort* __restrict__ Wproj_t, ushort* __restrict__ Wkvb) {
  __shared__ float t[32][33];
  int bid = blockIdx.x;
  if (bid < 2354) {
    const int i = bid * 256 + threadIdx.x;
    if (i < 3138 * 768 / 4) {
      float4 v = ((const float4*)x)[i];
      ushort4 o = {f2bf(v.x), f2bf(v.y), f2bf(v.z), f2bf(v.w)};
      ((ushort4*)xb)[i] = o;
    }
    return;
  }
  bid -= 2354;
  if (bid < 2880) {
    const float* W;
    ushort* Wt;
    int ldw, nbw;
    float scale;
    if (bid < 1728) {
      W = Wqkv; Wt = Wqkv_t; ldw = 2304; nbw = 72; scale = 1.f;
    } else if (bid < 2304) {
      bid -= 1728;
      W = Wq; Wt = Wq_t; ldw = 768; nbw = 24; scale = kScale;
    } else {
      bid -= 2304;
      W = Wproj; Wt = Wproj_t; ldw = 768; nbw = 24; scale = 1.f;
    }
    const int nb = (bid % nbw) * 32, kb = (bid / nbw) * 32;
    const int tx = threadIdx.x & 31, ty = threadIdx.x >> 5;
#pragma unroll
    for (int i = 0; i < 32; i += 8)
      t[ty + i][tx] = W[(size_t)(kb + ty + i) * ldw + nb + tx];
    __syncthreads();
#pragma unroll
    for (int i = 0; i < 32; i += 8)
      Wt[(size_t)(nb + ty + i) * 768 + kb + tx] = f2bf(t[tx][ty + i] * scale);
    return;
  }
  bid -= 2880;
  const int i = bid * 256 + threadIdx.x;
  const int c = i / 192, j4 = i - c * 192;
  float4 v = *(const float4*)(Wkv + (size_t)c * 1536 + j4 * 4);
  ushort4 o = {f2bf(v.x), f2bf(v.y), f2bf(v.z), f2bf(v.w)};
  *(ushort4*)(Wkvb + (size_t)c * 768 + j4 * 4) = o;
}

// ---------- pack V transposed: Vt[bh*8+f][64][224] bf16 (coalesced) ----------
__global__ void pack_vt_k(const ushort* __restrict__ qkvb,
                          ushort* __restrict__ Vt) {
  const int idx = blockIdx.x * 256 + threadIdx.x;
  if (idx >= kBH * kF * kD * kPpad) return;
  const int n = idx % kPpad;
  const int j = (idx / kPpad) & 63;
  const int f = (idx / (kPpad * kD)) & 7;
  const int bh = idx / (kPpad * kD * kF);
  const int b = bh / kH, h = bh % kH;
  ushort v = 0;
  if (n < kP)
    v = qkvb[(size_t)(b * kN + 1 + f * kP + n) * k3C + 2 * kC + h * kD + j];
  Vt[idx] = v;
}

// ---------- spatial attention, swapped-QK^T, LDS-free (r9 proven config) ----
__global__ __launch_bounds__(256) void sp_attn_mfma(
    const ushort* __restrict__ Qb, const ushort* __restrict__ Kb,
    const ushort* __restrict__ Vt, ushort* __restrict__ x4b) {
  const int w = threadIdx.x >> 6;
  const int lane = threadIdx.x & 63;
  const int fbh = blockIdx.x;
  const int f = fbh / 24, bh = fbh % 24;
  const int tile = blockIdx.y * 4 + w;  // 0..48 valid
  if (tile >= 49) return;
  const int q0 = tile * 32;
  const int lr = lane & 15;
  const int lg = lane >> 4;

  const ushort* qrow = Qb + ((size_t)bh * kS + q0 + lr) * kD + lg * 8;
  const bf16x8 a00 = *(const bf16x8*)qrow;
  const bf16x8 a01 = *(const bf16x8*)(qrow + 32);
  const bf16x8 a10 = *(const bf16x8*)(qrow + 16 * kD);
  const bf16x8 a11 = *(const bf16x8*)(qrow + 16 * kD + 32);

  f32x4 s0[13], s1[13];
  const ushort* kbase = Kb + ((size_t)bh * kS + f * kP + lr) * kD + lg * 8;
#pragma unroll
  for (int nt = 0; nt < 13; ++nt) {
    const ushort* kr = kbase + (size_t)nt * 16 * kD;
    bf16x8 b0 = *(const bf16x8*)kr;
    bf16x8 b1 = *(const bf16x8*)(kr + 32);
    f32x4 acc0 = {0.f, 0.f, 0.f, 0.f}, acc1 = {0.f, 0.f, 0.f, 0.f};
    acc0 = __builtin_amdgcn_mfma_f32_16x16x32_bf16(b0, a00, acc0, 0, 0, 0);
    acc0 = __builtin_amdgcn_mfma_f32_16x16x32_bf16(b1, a01, acc0, 0, 0, 0);
    acc1 = __builtin_amdgcn_mfma_f32_16x16x32_bf16(b0, a10, acc1, 0, 0, 0);
    acc1 = __builtin_amdgcn_mfma_f32_16x16x32_bf16(b1, a11, acc1, 0, 0, 0);
    s0[nt] = acc0;
    s1[nt] = acc1;
  }
  if (lg >= 1) {
#pragma unroll
    for (int r = 0; r < 4; ++r) { s0[12][r] = -1e30f; s1[12][r] = -1e30f; }
  }

  float m0 = -1e30f, m1 = -1e30f;
#pragma unroll
  for (int nt = 0; nt < 13; ++nt)
#pragma unroll
    for (int r = 0; r < 4; ++r) {
      m0 = fmaxf(m0, s0[nt][r]);
      m1 = fmaxf(m1, s1[nt][r]);
    }
  m0 = fmaxf(m0, __shfl_xor(m0, 16));
  m0 = fmaxf(m0, __shfl_xor(m0, 32));
  m1 = fmaxf(m1, __shfl_xor(m1, 16));
  m1 = fmaxf(m1, __shfl_xor(m1, 32));

  float sum0 = 0.f, sum1 = 0.f;
  u32x4 breg0[7], breg1[7];
#pragma unroll
  for (int blk = 0; blk < 7; ++blk) {
    unsigned pk0[2][2], pk1[2][2];
#pragma unroll
    for (int t = 0; t < 2; ++t) {
      const int nt = blk * 2 + t;
      if (nt < 13) {
        float e0 = __expf(s0[nt][0] - m0), e1 = __expf(s0[nt][1] - m0);
        float e2 = __expf(s0[nt][2] - m0), e3 = __expf(s0[nt][3] - m0);
        sum0 += (e0 + e1) + (e2 + e3);
        pk0[t][0] = ((unsigned)f2bf(e1) << 16) | f2bf(e0);
        pk0[t][1] = ((unsigned)f2bf(e3) << 16) | f2bf(e2);
        float g0 = __expf(s1[nt][0] - m1), g1 = __expf(s1[nt][1] - m1);
        float g2 = __expf(s1[nt][2] - m1), g3 = __expf(s1[nt][3] - m1);
        sum1 += (g0 + g1) + (g2 + g3);
        pk1[t][0] = ((unsigned)f2bf(g1) << 16) | f2bf(g0);
        pk1[t][1] = ((unsigned)f2bf(g3) << 16) | f2bf(g2);
      } else {
        pk0[t][0] = 0; pk0[t][1] = 0;
        pk1[t][0] = 0; pk1[t][1] = 0;
      }
    }
#pragma unroll
    for (int j2 = 0; j2 < 4; ++j2) {
      const int srcLane = ((lg & 1) * 2 + (j2 >> 1)) * 16 + lr;
      unsigned t0 = (unsigned)__shfl((int)pk0[0][j2 & 1], srcLane);
      unsigned t1 = (unsigned)__shfl((int)pk0[1][j2 & 1], srcLane);
      breg0[blk][j2] = (lg < 2) ? t0 : t1;
      unsigned u0 = (unsigned)__shfl((int)pk1[0][j2 & 1], srcLane);
      unsigned u1 = (unsigned)__shfl((int)pk1[1][j2 & 1], srcLane);
      breg1[blk][j2] = (lg < 2) ? u0 : u1;
    }
  }
  sum0 += __shfl_xor(sum0, 16);
  sum0 += __shfl_xor(sum0, 32);
  sum1 += __shfl_xor(sum1, 16);
  sum1 += __shfl_xor(sum1, 32);
  const float inv0 = 1.f / sum0, inv1 = 1.f / sum1;

  const ushort* vbase = Vt + ((size_t)(bh * kF + f) * kD + lr) * kPpad + lg * 8;
  f32x4 o0[4] = {}, o1[4] = {};
#pragma unroll
  for (int nt2 = 0; nt2 < 4; ++nt2) {
    const ushort* vb = vbase + (size_t)nt2 * 16 * kPpad;
#pragma unroll
    for (int blk = 0; blk < 7; ++blk) {
      bf16x8 av = *(const bf16x8*)(vb + blk * 32);
      bf16x8 pb0 = __builtin_bit_cast(bf16x8, breg0[blk]);
      bf16x8 pb1 = __builtin_bit_cast(bf16x8, breg1[blk]);
      o0[nt2] = __builtin_amdgcn_mfma_f32_16x16x32_bf16(av, pb0, o0[nt2], 0, 0, 0);
      o1[nt2] = __builtin_amdgcn_mfma_f32_16x16x32_bf16(av, pb1, o1[nt2], 0, 0, 0);
    }
  }

  const int b = bh / kH, h = bh % kH;
  const size_t base0 =
      ((size_t)(b * kS + q0 + lr) * kF + f) * kC + h * kD + lg * 4;
#pragma unroll
  for (int nt2 = 0; nt2 < 4; ++nt2) {
    ushort4 v0, v1;
    v0.x = f2bf(o0[nt2][0] * inv0);
    v0.y = f2bf(o0[nt2][1] * inv0);
    v0.z = f2bf(o0[nt2][2] * inv0);
    v0.w = f2bf(o0[nt2][3] * inv0);
    *(ushort4*)(x4b + base0 + nt2 * 16) = v0;
    v1.x = f2bf(o1[nt2][0] * inv1);
    v1.y = f2bf(o1[nt2][1] * inv1);
    v1.z = f2bf(o1[nt2][2] * inv1);
    v1.w = f2bf(o1[nt2][3] * inv1);
    *(ushort4*)(x4b + base0 + (size_t)16 * kF * kC + nt2 * 16) = v1;
  }
}

// ---------- cls attention, 4-phase parallel (bf16 qkv) ----------
__global__ __launch_bounds__(256) void cls_logits_k(const ushort* __restrict__ qkvb,
                                                    float* __restrict__ logits) {
  const int chunk = blockIdx.x, bh = blockIdx.y;
  const int b = bh / kH, h = bh % kH;
  const int g = threadIdx.x & 15, row = threadIdx.x >> 4;
  const size_t base = (size_t)b * kN * k3C;
  const ushort* qp = qkvb + base + h * kD + g * 4;
  const float q0 = bf2f(qp[0]) * kScale, q1 = bf2f(qp[1]) * kScale;
  const float q2 = bf2f(qp[2]) * kScale, q3 = bf2f(qp[3]) * kScale;
#pragma unroll
  for (int i = 0; i < 16; ++i) {
    const int n = chunk * 256 + i * 16 + row;
    if (n < kN) {
      ushort4 kv =
          *(const ushort4*)(qkvb + base + (size_t)n * k3C + kC + h * kD + g * 4);
      float p = q0 * bf2f(kv.x) + q1 * bf2f(kv.y) + q2 * bf2f(kv.z) +
                q3 * bf2f(kv.w);
#pragma unroll
      for (int o = 8; o; o >>= 1) p += __shfl_xor(p, o, 16);
      if (g == 0) logits[bh * kLpad + n] = p;
    }
  }
}

__global__ __launch_bounds__(256) void cls_softmax_k(const float* __restrict__ logits,
                                                     float* __restrict__ pbuf) {
  __shared__ float red[8];
  const int bh = blockIdx.x, tid = threadIdx.x;
  float m = -1e30f;
  for (int n = tid; n < kN; n += 256) m = fmaxf(m, logits[bh * kLpad + n]);
#pragma unroll
  for (int o = 32; o; o >>= 1) m = fmaxf(m, __shfl_xor(m, o));
  if ((tid & 63) == 0) red[tid >> 6] = m;
  __syncthreads();
  m = fmaxf(fmaxf(red[0], red[1]), fmaxf(red[2], red[3]));
  float sum = 0.f;
  for (int n = tid; n < kN; n += 256) sum += __expf(logits[bh * kLpad + n] - m);
#pragma unroll
  for (int o = 32; o; o >>= 1) sum += __shfl_xor(sum, o);
  if ((tid & 63) == 0) red[4 + (tid >> 6)] = sum;
  __syncthreads();
  const float inv = 1.f / (red[4] + red[5] + red[6] + red[7]);
  for (int n = tid; n < kN; n += 256)
    pbuf[bh * kLpad + n] = __expf(logits[bh * kLpad + n] - m) * inv;
}

__global__ __launch_bounds__(256) void cls_pv_k(const ushort* __restrict__ qkvb,
                                                const float* __restrict__ pbuf,
                                                float* __restrict__ partial) {
  __shared__ float pb[256];
  const int chunk = blockIdx.x, bh = blockIdx.y;
  const int b = bh / kH, h = bh % kH;
  const int j = threadIdx.x & 63, part = threadIdx.x >> 6;
  const size_t base = (size_t)b * kN * k3C + 2 * kC + h * kD + j;
  float acc = 0.f;
#pragma unroll 4
  for (int i = 0; i < 64; ++i) {
    const int n = chunk * 256 + i * 4 + part;
    if (n < kN)
      acc = fmaf(pbuf[bh * kLpad + n], bf2f(qkvb[base + (size_t)n * k3C]), acc);
  }
  pb[threadIdx.x] = acc;
  __syncthreads();
  if (part == 0)
    partial[((size_t)bh * 7 + chunk) * kD + j] =
        pb[j] + pb[64 + j] + pb[128 + j] + pb[192 + j];
}

__global__ void cls_red_k(const float* __restrict__ partial,
                          ushort* __restrict__ xin_b) {
  const int bh = blockIdx.x, j = threadIdx.x;
  const int b = bh / kH, h = bh % kH;
  float s = 0.f;
#pragma unroll
  for (int c = 0; c < 7; ++c) s += partial[((size_t)bh * 7 + c) * kD + j];
  xin_b[(size_t)(b * kN) * kC + h * kD + j] = f2bf(s);
}

// ---------- fused temporal attention: one block per (b,s) ----------
// x4 staged in LDS (reused 12x); w2 read DIRECTLY from global (each byte
// consumed exactly once -> staging was pure overhead and capped occupancy
// at 5 blocks/CU via 30.7KB LDS; now 12.3KB).
__global__ __launch_bounds__(256) void attn2_fused(
    const ushort* __restrict__ x4b, const ushort* __restrict__ w2b,
    ushort* __restrict__ xin_b, float* __restrict__ attn2out) {
  __shared__ __align__(16) ushort x4s[kF * kC];  // 12 KB
  const int bs = blockIdx.x;
  const int b = bs / kS, s = bs - b * kS;
  const int tid = threadIdx.x;
  {
    const ulonglong2* src = (const ulonglong2*)(x4b + (size_t)bs * kF * kC);
    ulonglong2* dst = (ulonglong2*)x4s;
    for (int i = tid; i < kF * kC / 8; i += 256) dst[i] = src[i];
  }
  __syncthreads();
  const int w = tid >> 6, lane = tid & 63;
  const ushort* w2row = w2b + (size_t)bs * kH * kC;
#pragma unroll
  for (int hh = 0; hh < 3; ++hh) {
    const int h = w * 3 + hh;
    float part[kF] = {};
#pragma unroll
    for (int i = 0; i < 3; ++i) {
      const int c = lane * 4 + i * 256;
      ushort4 wv = *(const ushort4*)(w2row + h * kC + c);
      const float w0 = bf2f(wv.x), w1 = bf2f(wv.y);
      const float w2v = bf2f(wv.z), w3 = bf2f(wv.w);
#pragma unroll
      for (int f = 0; f < kF; ++f) {
        ushort4 xv = *(const ushort4*)&x4s[f * kC + c];
        part[f] += bf2f(xv.x) * w0 + bf2f(xv.y) * w1 + bf2f(xv.z) * w2v +
                   bf2f(xv.w) * w3;
      }
    }
    float l[kF];
#pragma unroll
    for (int f = 0; f < kF; ++f) {
      float p = part[f];
#pragma unroll
      for (int o = 32; o; o >>= 1) p += __shfl_xor(p, o);
      l[f] = p;
    }
    float m = l[0];
#pragma unroll
    for (int f = 1; f < kF; ++f) m = fmaxf(m, l[f]);
    float sum = 0.f;
#pragma unroll
    for (int f = 0; f < kF; ++f) {
      l[f] = __expf(l[f] - m);
      sum += l[f];
    }
    const float inv = 1.f / sum;
    float pv = 0.f;
#pragma unroll
    for (int f = 0; f < kF; ++f) pv = (lane == f) ? l[f] : pv;
    if (lane < kF)
      attn2out[((size_t)(b * kH + h) * kS + s) * kF + lane] = pv * inv;
    float o = 0.f;
#pragma unroll
    for (int f = 0; f < kF; ++f)
      o = fmaf(l[f] * inv, bf2f(x4s[f * kC + h * kD + lane]), o);
    xin_b[(size_t)(b * kN + 1 + s) * kC + h * kD + lane] = f2bf(o);
  }
}

extern "C" void kernel_launch(void* const* d_in, const int* in_sizes, int n_in,
                              void* d_out, int out_size, void* d_ws,
                              size_t ws_size, hipStream_t stream) {
  const float* x = (const float*)d_in[0];
  const float* Wqkv = (const float*)d_in[1];
  const float* Wq = (const float*)d_in[2];
  const float* Wkv = (const float*)d_in[3];
  const float* Wproj = (const float*)d_in[4];
  const float* bproj = (const float*)d_in[5];

  char* p = (char*)d_ws;
  ushort* qkvb = (ushort*)p;         p += (size_t)3138 * 2304 * 2;
  ushort* w2b = (ushort*)p;          p += (size_t)kBS * kH * kC * 2;
  ushort* q2b = (ushort*)p;          p += (size_t)kBS * kC * 2;
  ushort* x4b = (ushort*)p;          p += (size_t)25088 * 768 * 2;
  ushort* xin_b = (ushort*)p;        p += (size_t)3138 * 768 * 2;
  ushort* xb = (ushort*)p;           p += (size_t)3138 * 768 * 2;
  ushort* Wqkv_t = (ushort*)p;       p += (size_t)2304 * 768 * 2;
  ushort* Wq_t = (ushort*)p;         p += (size_t)768 * 768 * 2;
  ushort* Wkvb = (ushort*)p;         p += (size_t)768 * 768 * 2;
  ushort* Wproj_t = (ushort*)p;      p += (size_t)768 * 768 * 2;
  ushort* Qb = (ushort*)p;           p += (size_t)kBH * kS * kD * 2;
  ushort* Kb = (ushort*)p;           p += ((size_t)kBH * kS + 16) * kD * 2;
  ushort* Vt = (ushort*)p;           p += (size_t)kBH * kF * kD * kPpad * 2;
  float* clsL = (float*)p;           p += (size_t)kBH * kLpad * 4;
  float* clsP = (float*)p;           p += (size_t)kBH * kLpad * 4;
  float* clsPart = (float*)p;

  float* out = (float*)d_out;
  float* attn2 = out + (size_t)kB * kN * kC;

  // 0. merged packs (x + 4 weights)
  pack_all_k<<<5810, 256, 0, stream>>>(x, Wqkv, Wq, Wproj, Wkv, xb, Wqkv_t,
                                       Wq_t, Wproj_t, Wkvb);
  // 1. qkv GEMM with fused Qb/Kb pack -> qkvb, Qb, Kb
  gemm_qkv<<<18 * 25, 256, 0, stream>>>(xb, Wqkv_t, qkvb, Qb, Kb);
  // 2. Vt pack (coalesced)
  pack_vt_k<<<(kBH * kF * kD * kPpad + 255) / 256, 256, 0, stream>>>(qkvb, Vt);
  // 3. cls attention (4-phase)
  cls_logits_k<<<dim3(7, 24), 256, 0, stream>>>(qkvb, clsL);
  cls_softmax_k<<<24, 256, 0, stream>>>(clsL, clsP);
  cls_pv_k<<<dim3(7, 24), 256, 0, stream>>>(qkvb, clsP, clsPart);
  cls_red_k<<<24, 64, 0, stream>>>(clsPart, xin_b);
  // 4. spatial attention -> x4b (r9 config)
  sp_attn_mfma<<<dim3(192, 13), 256, 0, stream>>>(Qb, Kb, Vt, x4b);
  // 5. q2 = diag(x4) @ (Wq*scale)
  gemm_q2<<<6 * 25, 256, 0, stream>>>(x4b, Wq_t, q2b);
  // 6. w2[bs,h,:] = Wkv_h^T @ q2[bs,h,:]
  w2_gemm<<<1800, 256, 0, stream>>>(q2b, Wkvb, w2b);
  // 7. fused temporal attention (w2 direct-read, x4-only LDS)
  attn2_fused<<<kBS, 256, 0, stream>>>(x4b, w2b, xin_b, attn2);
  // 8. out = xin @ Wproj + bproj
  gemm_bf16<float><<<6 * 25, 256, 0, stream>>>(xin_b, Wproj_t, bproj, out, 3138,
                                               768, 768, 6);
}